// Round 1
// baseline (522.416 us; speedup 1.0000x reference)
//
#include <hip/hip_runtime.h>

#define BB 8
#define SS 2048
#define DD 1024
#define BDD 512
#define NSP 64

typedef __attribute__((ext_vector_type(8))) short bf16x8;
typedef __attribute__((ext_vector_type(4))) float f32x4;
typedef unsigned short u16;
typedef unsigned int u32;

__device__ __forceinline__ u16 f2bf(float f) {
  u32 u = __builtin_bit_cast(u32, f);
  u = u + 0x7fffu + ((u >> 16) & 1u);
  return (u16)(u >> 16);
}

__device__ __forceinline__ void gl_lds16(const void* g, void* l) {
  __builtin_amdgcn_global_load_lds((const __attribute__((address_space(1))) void*)g,
                                   (__attribute__((address_space(3))) void*)l,
                                   16, 0, 0);
}

// ---------- convert 8 f32 -> 8 bf16 per thread ----------
__global__ void k_cvt8(const float* __restrict__ in, u16* __restrict__ outp) {
  int i = (blockIdx.x * 256 + threadIdx.x) * 8;
  float4 a = *(const float4*)(in + i);
  float4 b = *(const float4*)(in + i + 4);
  uint4 v;
  v.x = f2bf(a.x) | ((u32)f2bf(a.y) << 16);
  v.y = f2bf(a.z) | ((u32)f2bf(a.w) << 16);
  v.z = f2bf(b.x) | ((u32)f2bf(b.y) << 16);
  v.w = f2bf(b.z) | ((u32)f2bf(b.w) << 16);
  *(uint4*)(outp + i) = v;
}

// ---------- gate_W [k][n] f32 -> gwt [n][k] bf16 (transpose) ----------
__global__ void k_gatewt(const float* __restrict__ gw, u16* __restrict__ gwt) {
  __shared__ float tile[32][33];
  int n0 = blockIdx.x * 32, k0 = blockIdx.y * 32;
  int tx = threadIdx.x & 31, ty = threadIdx.x >> 5;  // ty 0..7
#pragma unroll
  for (int r = 0; r < 4; ++r) {
    int kr = ty + r * 8;
    tile[kr][tx] = gw[(k0 + kr) * DD + n0 + tx];
  }
  __syncthreads();
#pragma unroll
  for (int r = 0; r < 4; ++r) {
    int nc = ty + r * 8;
    gwt[(n0 + nc) * DD + k0 + tx] = f2bf(tile[tx][nc]);
  }
}

// ---------- totals -> reciprocal ----------
__global__ void k_tot(const float* __restrict__ infl, float* __restrict__ rtot) {
  __shared__ float red[16][64];
  int b = blockIdx.x;
  int kq = threadIdx.x & 15, q = threadIdx.x >> 4;  // q 0..15
  float a0 = 0.f, a1 = 0.f, a2 = 0.f, a3 = 0.f;
  for (int i = 0; i < 128; ++i) {
    int s = q * 128 + i;
    float4 v = *(const float4*)(infl + (b * SS + s) * NSP + kq * 4);
    a0 += v.x; a1 += v.y; a2 += v.z; a3 += v.w;
  }
  red[q][kq * 4 + 0] = a0;
  red[q][kq * 4 + 1] = a1;
  red[q][kq * 4 + 2] = a2;
  red[q][kq * 4 + 3] = a3;
  __syncthreads();
  if (threadIdx.x < 64) {
    float tt = 0.f;
#pragma unroll
    for (int qq = 0; qq < 16; ++qq) tt += red[qq][threadIdx.x];
    rtot[b * NSP + threadIdx.x] = 1.f / fmaxf(tt, 1e-8f);
  }
}

// ---------- gather: gath[b][k][d] = (sum_s infl[b][s][k]*tok[b][s][d]) * rtot ----------
__global__ void k_gather(const float* __restrict__ tok, const float* __restrict__ infl,
                         const float* __restrict__ rtot, float* __restrict__ gath) {
  __shared__ float red[8][8][32];
  int dt = blockIdx.x;  // 0..31 (32 d per tile)
  int b = blockIdx.y;
  int dl = threadIdx.x & 31, q = threadIdx.x >> 5;  // q 0..7
  int d = dt * 32 + dl;
  float acc[64];
#pragma unroll
  for (int k = 0; k < 64; ++k) acc[k] = 0.f;
  for (int i = 0; i < 256; ++i) {
    int s = q * 256 + i;
    float tv = tok[(b * SS + s) * DD + d];
    const float* ip = infl + (b * SS + s) * NSP;
#pragma unroll
    for (int kk = 0; kk < 16; ++kk) {
      float4 wv = *(const float4*)(ip + kk * 4);
      acc[kk * 4 + 0] += wv.x * tv;
      acc[kk * 4 + 1] += wv.y * tv;
      acc[kk * 4 + 2] += wv.z * tv;
      acc[kk * 4 + 3] += wv.w * tv;
    }
  }
#pragma unroll
  for (int c = 0; c < 8; ++c) {
#pragma unroll
    for (int j = 0; j < 8; ++j) red[q][j][dl] = acc[c * 8 + j];
    __syncthreads();
    int j2 = threadIdx.x >> 5, d2 = threadIdx.x & 31;
    float sum = 0.f;
#pragma unroll
    for (int qq = 0; qq < 8; ++qq) sum += red[qq][j2][d2];
    int k = c * 8 + j2;
    gath[(b * NSP + k) * DD + dt * 32 + d2] = sum * rtot[b * NSP + k];
    __syncthreads();
  }
}

// ---------- encoder: enc = relu(gath @ encW + encB) ----------
__global__ void k_enc(const float* __restrict__ gath, const float* __restrict__ encW,
                      const float* __restrict__ encB, float* __restrict__ enc) {
  int nh = blockIdx.x, mt = blockIdx.y;
  int m0 = mt * 8;
  int n = nh * 256 + threadIdx.x;
  float acc[8];
#pragma unroll
  for (int m = 0; m < 8; ++m) acc[m] = 0.f;
  for (int dq = 0; dq < 256; ++dq) {
    int d = dq * 4;
    float w0 = encW[(d + 0) * BDD + n];
    float w1 = encW[(d + 1) * BDD + n];
    float w2 = encW[(d + 2) * BDD + n];
    float w3 = encW[(d + 3) * BDD + n];
#pragma unroll
    for (int m = 0; m < 8; ++m) {
      float4 g = *(const float4*)(gath + (m0 + m) * DD + d);
      acc[m] += g.x * w0 + g.y * w1 + g.z * w2 + g.w * w3;
    }
  }
  float eb = encB[n];
#pragma unroll
  for (int m = 0; m < 8; ++m)
    enc[(m0 + m) * BDD + n] = fmaxf(acc[m] + eb, 0.f);
}

// ---------- per-splat transform: trf[b][ks][n] = enc[b][ks][:] @ trW[ks] + trB[ks] ----------
__global__ void k_trans(const float* __restrict__ enc, const float* __restrict__ trW,
                        const float* __restrict__ trB, float* __restrict__ trf) {
  __shared__ float red[2][8][128];
  int nq = blockIdx.x, ks = blockIdx.y;
  int nl = threadIdx.x & 127, dh = threadIdx.x >> 7;
  int n = nq * 128 + nl;
  float acc[8];
#pragma unroll
  for (int m = 0; m < 8; ++m) acc[m] = 0.f;
  for (int dq = 0; dq < 64; ++dq) {
    int d = dh * 256 + dq * 4;
    float w0 = trW[(ks * BDD + d + 0) * BDD + n];
    float w1 = trW[(ks * BDD + d + 1) * BDD + n];
    float w2 = trW[(ks * BDD + d + 2) * BDD + n];
    float w3 = trW[(ks * BDD + d + 3) * BDD + n];
#pragma unroll
    for (int m = 0; m < 8; ++m) {
      float4 e = *(const float4*)(enc + (m * NSP + ks) * BDD + d);
      acc[m] += e.x * w0 + e.y * w1 + e.z * w2 + e.w * w3;
    }
  }
#pragma unroll
  for (int m = 0; m < 8; ++m) red[dh][m][nl] = acc[m];
  __syncthreads();
  if (dh == 0) {
    float tb = trB[ks * BDD + n];
#pragma unroll
    for (int m = 0; m < 8; ++m)
      trf[(m * NSP + ks) * BDD + n] = red[0][m][nl] + red[1][m][nl] + tb;
  }
}

// ---------- decoder: decT[b][n][ks] = bf16(trf[b][ks][:] @ decW[:, n] + decB[n]) ----------
__global__ void k_dec(const float* __restrict__ trf, const float* __restrict__ decW,
                      const float* __restrict__ decB, u16* __restrict__ decT) {
  __shared__ u16 dt_lds[8][256];
  int nq = blockIdx.x, mt = blockIdx.y;
  int m0 = mt * 8;
  int n = nq * 256 + threadIdx.x;
  float acc[8];
#pragma unroll
  for (int m = 0; m < 8; ++m) acc[m] = 0.f;
  for (int dq = 0; dq < 128; ++dq) {
    int d = dq * 4;
    float w0 = decW[(d + 0) * DD + n];
    float w1 = decW[(d + 1) * DD + n];
    float w2 = decW[(d + 2) * DD + n];
    float w3 = decW[(d + 3) * DD + n];
#pragma unroll
    for (int m = 0; m < 8; ++m) {
      float4 x = *(const float4*)(trf + (m0 + m) * BDD + d);
      acc[m] += x.x * w0 + x.y * w1 + x.z * w2 + x.w * w3;
    }
  }
  float db = decB[n];
  int b = m0 >> 6, ks0 = m0 & 63;
#pragma unroll
  for (int m = 0; m < 8; ++m) dt_lds[m][threadIdx.x] = f2bf(acc[m] + db);
  __syncthreads();
  int j = threadIdx.x;
  uint4 v;
  v.x = dt_lds[0][j] | ((u32)dt_lds[1][j] << 16);
  v.y = dt_lds[2][j] | ((u32)dt_lds[3][j] << 16);
  v.z = dt_lds[4][j] | ((u32)dt_lds[5][j] << 16);
  v.w = dt_lds[6][j] | ((u32)dt_lds[7][j] << 16);
  *(uint4*)(decT + (b * DD + nq * 256 + j) * NSP + ks0) = v;
}

// ---------- fused gate GEMM (bf16 MFMA) + scatter MFMA + sigmoid*flow ----------
__global__ __launch_bounds__(256) void k_out(const u16* __restrict__ tokbf,
                                             const u16* __restrict__ gwt,
                                             const u16* __restrict__ inflbf,
                                             const u16* __restrict__ decT,
                                             const float* __restrict__ gateB,
                                             float* __restrict__ outp) {
  __shared__ u16 As[128 * 64];
  __shared__ u16 Bs[128 * 64];
  int t = threadIdx.x;
  int l = t & 63, w = t >> 6;
  int wr = w >> 1, wc = w & 1;
  int m0 = blockIdx.x * 128, n0 = blockIdx.y * 128;
  int l15 = l & 15, lh = l >> 4;
  int srow = t >> 3, scol = (t & 7) * 8;

  f32x4 accg[4][4];
#pragma unroll
  for (int i = 0; i < 4; ++i)
#pragma unroll
    for (int j = 0; j < 4; ++j) accg[i][j] = (f32x4){0.f, 0.f, 0.f, 0.f};

  for (int kt = 0; kt < 16; ++kt) {
    int k0 = kt * 64;
#pragma unroll
    for (int iss = 0; iss < 4; ++iss) {
      int row = iss * 32 + srow;
      gl_lds16(tokbf + (m0 + row) * DD + k0 + scol, &As[row * 64 + scol]);
      gl_lds16(gwt + (n0 + row) * DD + k0 + scol, &Bs[row * 64 + scol]);
    }
    __syncthreads();
#pragma unroll
    for (int ks = 0; ks < 2; ++ks) {
      bf16x8 af[4], bfv[4];
#pragma unroll
      for (int mi = 0; mi < 4; ++mi)
        af[mi] = *(const bf16x8*)&As[(wr * 64 + mi * 16 + l15) * 64 + ks * 32 + lh * 8];
#pragma unroll
      for (int ni = 0; ni < 4; ++ni)
        bfv[ni] = *(const bf16x8*)&Bs[(wc * 64 + ni * 16 + l15) * 64 + ks * 32 + lh * 8];
#pragma unroll
      for (int mi = 0; mi < 4; ++mi)
#pragma unroll
        for (int ni = 0; ni < 4; ++ni)
          accg[mi][ni] = __builtin_amdgcn_mfma_f32_16x16x32_bf16(af[mi], bfv[ni], accg[mi][ni], 0, 0, 0);
    }
    __syncthreads();
  }

  // scatter pass: flow tile via 2 more k-steps (K = 64 splats), reusing LDS
  int b = m0 >> 11;
  int s0 = m0 & 2047;
#pragma unroll
  for (int iss = 0; iss < 4; ++iss) {
    int row = iss * 32 + srow;
    gl_lds16(inflbf + (b * SS + s0 + row) * NSP + scol, &As[row * 64 + scol]);
    gl_lds16(decT + (b * DD + n0 + row) * NSP + scol, &Bs[row * 64 + scol]);
  }
  __syncthreads();
  f32x4 accf[4][4];
#pragma unroll
  for (int i = 0; i < 4; ++i)
#pragma unroll
    for (int j = 0; j < 4; ++j) accf[i][j] = (f32x4){0.f, 0.f, 0.f, 0.f};
#pragma unroll
  for (int ks = 0; ks < 2; ++ks) {
    bf16x8 af[4], bfv[4];
#pragma unroll
    for (int mi = 0; mi < 4; ++mi)
      af[mi] = *(const bf16x8*)&As[(wr * 64 + mi * 16 + l15) * 64 + ks * 32 + lh * 8];
#pragma unroll
    for (int ni = 0; ni < 4; ++ni)
      bfv[ni] = *(const bf16x8*)&Bs[(wc * 64 + ni * 16 + l15) * 64 + ks * 32 + lh * 8];
#pragma unroll
    for (int mi = 0; mi < 4; ++mi)
#pragma unroll
      for (int ni = 0; ni < 4; ++ni)
        accf[mi][ni] = __builtin_amdgcn_mfma_f32_16x16x32_bf16(af[mi], bfv[ni], accf[mi][ni], 0, 0, 0);
  }

  float gb[4];
#pragma unroll
  for (int ni = 0; ni < 4; ++ni) gb[ni] = gateB[n0 + wc * 64 + ni * 16 + l15];
#pragma unroll
  for (int mi = 0; mi < 4; ++mi)
#pragma unroll
    for (int ni = 0; ni < 4; ++ni)
#pragma unroll
      for (int r = 0; r < 4; ++r) {
        int mr = m0 + wr * 64 + mi * 16 + lh * 4 + r;
        int nc = n0 + wc * 64 + ni * 16 + l15;
        float z = accg[mi][ni][r] + gb[ni];
        float gate = 1.f / (1.f + __expf(-z));
        outp[mr * DD + nc] = accf[mi][ni][r] * gate;
      }
}

extern "C" void kernel_launch(void* const* d_in, const int* in_sizes, int n_in,
                              void* d_out, int out_size, void* d_ws, size_t ws_size,
                              hipStream_t stream) {
  const float* tok = (const float*)d_in[0];
  const float* infl = (const float*)d_in[1];
  const float* encW = (const float*)d_in[2];
  const float* encB = (const float*)d_in[3];
  const float* trW = (const float*)d_in[4];
  const float* trB = (const float*)d_in[5];
  const float* decW = (const float*)d_in[6];
  const float* decB = (const float*)d_in[7];
  const float* gw = (const float*)d_in[8];
  const float* gateB = (const float*)d_in[9];
  float* outp = (float*)d_out;

  char* wsp = (char*)d_ws;
  u16* tokbf = (u16*)(wsp);                    // 33,554,432 B
  u16* gwt = (u16*)(wsp + 33554432);           //  2,097,152 B
  u16* inflbf = (u16*)(wsp + 35651584);        //  2,097,152 B
  float* rtot = (float*)(wsp + 37748736);      //      2,048 B
  float* gath = (float*)(wsp + 37750784);      //  2,097,152 B
  float* enc = (float*)(wsp + 39847936);       //  1,048,576 B
  float* trf = (float*)(wsp + 40896512);       //  1,048,576 B
  u16* decT = (u16*)(wsp + 41945088);          //  1,048,576 B  (end ~42.99 MB)

  k_cvt8<<<dim3(8192), dim3(256), 0, stream>>>(tok, tokbf);
  k_cvt8<<<dim3(512), dim3(256), 0, stream>>>(infl, inflbf);
  k_gatewt<<<dim3(32, 32), dim3(256), 0, stream>>>(gw, gwt);
  k_tot<<<dim3(8), dim3(256), 0, stream>>>(infl, rtot);
  k_gather<<<dim3(32, 8), dim3(256), 0, stream>>>(tok, infl, rtot, gath);
  k_enc<<<dim3(2, 64), dim3(256), 0, stream>>>(gath, encW, encB, enc);
  k_trans<<<dim3(4, 64), dim3(256), 0, stream>>>(enc, trW, trB, trf);
  k_dec<<<dim3(4, 64), dim3(256), 0, stream>>>(trf, decW, decB, decT);
  k_out<<<dim3(128, 8), dim3(256), 0, stream>>>(tokbf, gwt, inflbf, decT, gateB, outp);
}

// Round 2
// 349.829 us; speedup vs baseline: 1.4933x; 1.4933x over previous
//
#include <hip/hip_runtime.h>

#define BB 8
#define SS 2048
#define DD 1024
#define BDD 512
#define NSP 64

typedef __attribute__((ext_vector_type(8))) short bf16x8;
typedef __attribute__((ext_vector_type(4))) float f32x4;
typedef unsigned short u16;
typedef unsigned int u32;

__device__ __forceinline__ u16 f2bf(float f) {
  u32 u = __builtin_bit_cast(u32, f);
  u = u + 0x7fffu + ((u >> 16) & 1u);
  return (u16)(u >> 16);
}

__device__ __forceinline__ void gl_lds16(const void* g, void* l) {
  __builtin_amdgcn_global_load_lds((const __attribute__((address_space(1))) void*)g,
                                   (__attribute__((address_space(3))) void*)l,
                                   16, 0, 0);
}

// ---------- convert 8 f32 -> 8 bf16 per thread ----------
__global__ void k_cvt8(const float* __restrict__ in, u16* __restrict__ outp) {
  int i = (blockIdx.x * 256 + threadIdx.x) * 8;
  float4 a = *(const float4*)(in + i);
  float4 b = *(const float4*)(in + i + 4);
  uint4 v;
  v.x = f2bf(a.x) | ((u32)f2bf(a.y) << 16);
  v.y = f2bf(a.z) | ((u32)f2bf(a.w) << 16);
  v.z = f2bf(b.x) | ((u32)f2bf(b.y) << 16);
  v.w = f2bf(b.z) | ((u32)f2bf(b.w) << 16);
  *(uint4*)(outp + i) = v;
}

// ---------- bf16 transpose: in [b*2048+s][W] -> out [b][W][2048] ----------
// grid (W/64, totalRows/64), block 256
__global__ void k_transpose(const u16* __restrict__ in, u16* __restrict__ outp, int W) {
  __shared__ u16 tile[64][80];  // row stride 160B: 16B-aligned, read phase conflict-free
  int C0 = blockIdx.x * 64;
  int R0 = blockIdx.y * 64;
  int b = R0 >> 11;
  int s0 = R0 & 2047;
  int t = threadIdx.x;
  int lr = t >> 3, lc = (t & 7) * 8;
#pragma unroll
  for (int i = 0; i < 2; ++i) {
    int r = lr + i * 32;
    uint4 v = *(const uint4*)(in + (R0 + r) * W + C0 + lc);
    *(uint4*)&tile[r][lc] = v;
  }
  __syncthreads();
  int sseg = (t & 7) * 8;
#pragma unroll
  for (int i = 0; i < 2; ++i) {
    int dcol = (t >> 3) + i * 32;
    u16 a0 = tile[sseg + 0][dcol], a1 = tile[sseg + 1][dcol];
    u16 a2 = tile[sseg + 2][dcol], a3 = tile[sseg + 3][dcol];
    u16 a4 = tile[sseg + 4][dcol], a5 = tile[sseg + 5][dcol];
    u16 a6 = tile[sseg + 6][dcol], a7 = tile[sseg + 7][dcol];
    uint4 v;
    v.x = a0 | ((u32)a1 << 16);
    v.y = a2 | ((u32)a3 << 16);
    v.z = a4 | ((u32)a5 << 16);
    v.w = a6 | ((u32)a7 << 16);
    *(uint4*)(outp + (size_t)b * W * SS + (size_t)(C0 + dcol) * SS + s0 + sseg) = v;
  }
}

// ---------- gate_W [k][n] f32 -> gwt [n][k] bf16 (transpose) ----------
__global__ void k_gatewt(const float* __restrict__ gw, u16* __restrict__ gwt) {
  __shared__ float tile[32][33];
  int n0 = blockIdx.x * 32, k0 = blockIdx.y * 32;
  int tx = threadIdx.x & 31, ty = threadIdx.x >> 5;
#pragma unroll
  for (int r = 0; r < 4; ++r) {
    int kr = ty + r * 8;
    tile[kr][tx] = gw[(k0 + kr) * DD + n0 + tx];
  }
  __syncthreads();
#pragma unroll
  for (int r = 0; r < 4; ++r) {
    int nc = ty + r * 8;
    gwt[(n0 + nc) * DD + k0 + tx] = f2bf(tile[tx][nc]);
  }
}

// ---------- totals -> reciprocal ----------
__global__ void k_tot(const float* __restrict__ infl, float* __restrict__ rtot) {
  __shared__ float red[16][64];
  int b = blockIdx.x;
  int kq = threadIdx.x & 15, q = threadIdx.x >> 4;
  float a0 = 0.f, a1 = 0.f, a2 = 0.f, a3 = 0.f;
  for (int i = 0; i < 128; ++i) {
    int s = q * 128 + i;
    float4 v = *(const float4*)(infl + (b * SS + s) * NSP + kq * 4);
    a0 += v.x; a1 += v.y; a2 += v.z; a3 += v.w;
  }
  red[q][kq * 4 + 0] = a0;
  red[q][kq * 4 + 1] = a1;
  red[q][kq * 4 + 2] = a2;
  red[q][kq * 4 + 3] = a3;
  __syncthreads();
  if (threadIdx.x < 64) {
    float tt = 0.f;
#pragma unroll
    for (int qq = 0; qq < 16; ++qq) tt += red[qq][threadIdx.x];
    rtot[b * NSP + threadIdx.x] = 1.f / fmaxf(tt, 1e-8f);
  }
}

// ---------- MFMA gather: gath[b][k][d] = (sum_s inflT[b][k][s]*tokT[b][d][s]) * rtot ----------
// grid (16 dtile, 8 b), 256 threads
__global__ __launch_bounds__(256) void k_gather_mfma(const u16* __restrict__ inflT,
                                                     const u16* __restrict__ tokT,
                                                     const float* __restrict__ rtot,
                                                     float* __restrict__ gath) {
  __shared__ u16 As[64 * 64];  // infl tile: k x s
  __shared__ u16 Bs[64 * 64];  // tok tile:  d x s
  int t = threadIdx.x;
  int l = t & 63, w = t >> 6;
  int wr = w >> 1, wc = w & 1;
  int n0 = blockIdx.x * 64;
  int b = blockIdx.y;
  int l15 = l & 15, lh = l >> 4;
  int srow = t >> 3, scol = (t & 7) * 8;

  const u16* ap = inflT + (size_t)b * NSP * SS;
  const u16* bp = tokT + (size_t)b * DD * SS;

  f32x4 acc[2][2];
#pragma unroll
  for (int i = 0; i < 2; ++i)
#pragma unroll
    for (int j = 0; j < 2; ++j) acc[i][j] = (f32x4){0.f, 0.f, 0.f, 0.f};

  for (int kt = 0; kt < 32; ++kt) {
    int k0 = kt * 64;
#pragma unroll
    for (int i = 0; i < 2; ++i) {
      int row = srow + i * 32;
      gl_lds16(ap + row * SS + k0 + scol, &As[row * 64 + scol]);
      gl_lds16(bp + (n0 + row) * SS + k0 + scol, &Bs[row * 64 + scol]);
    }
    __syncthreads();
#pragma unroll
    for (int ks = 0; ks < 2; ++ks) {
      bf16x8 af[2], bfv[2];
#pragma unroll
      for (int mi = 0; mi < 2; ++mi)
        af[mi] = *(const bf16x8*)&As[(wr * 32 + mi * 16 + l15) * 64 + ks * 32 + lh * 8];
#pragma unroll
      for (int ni = 0; ni < 2; ++ni)
        bfv[ni] = *(const bf16x8*)&Bs[(wc * 32 + ni * 16 + l15) * 64 + ks * 32 + lh * 8];
#pragma unroll
      for (int mi = 0; mi < 2; ++mi)
#pragma unroll
        for (int ni = 0; ni < 2; ++ni)
          acc[mi][ni] = __builtin_amdgcn_mfma_f32_16x16x32_bf16(af[mi], bfv[ni], acc[mi][ni], 0, 0, 0);
    }
    __syncthreads();
  }

  float rt[2][4];
#pragma unroll
  for (int mi = 0; mi < 2; ++mi)
#pragma unroll
    for (int r = 0; r < 4; ++r)
      rt[mi][r] = rtot[b * NSP + wr * 32 + mi * 16 + lh * 4 + r];
#pragma unroll
  for (int mi = 0; mi < 2; ++mi)
#pragma unroll
    for (int ni = 0; ni < 2; ++ni)
#pragma unroll
      for (int r = 0; r < 4; ++r) {
        int krow = wr * 32 + mi * 16 + lh * 4 + r;
        int dcol = n0 + wc * 32 + ni * 16 + l15;
        gath[((size_t)b * NSP + krow) * DD + dcol] = acc[mi][ni][r] * rt[mi][r];
      }
}

// ---------- encoder: enc = relu(gath @ encW + encB) ----------
__global__ void k_enc(const float* __restrict__ gath, const float* __restrict__ encW,
                      const float* __restrict__ encB, float* __restrict__ enc) {
  int nh = blockIdx.x, mt = blockIdx.y;
  int m0 = mt * 8;
  int n = nh * 256 + threadIdx.x;
  float acc[8];
#pragma unroll
  for (int m = 0; m < 8; ++m) acc[m] = 0.f;
  for (int dq = 0; dq < 256; ++dq) {
    int d = dq * 4;
    float w0 = encW[(d + 0) * BDD + n];
    float w1 = encW[(d + 1) * BDD + n];
    float w2 = encW[(d + 2) * BDD + n];
    float w3 = encW[(d + 3) * BDD + n];
#pragma unroll
    for (int m = 0; m < 8; ++m) {
      float4 g = *(const float4*)(gath + (m0 + m) * DD + d);
      acc[m] += g.x * w0 + g.y * w1 + g.z * w2 + g.w * w3;
    }
  }
  float eb = encB[n];
#pragma unroll
  for (int m = 0; m < 8; ++m)
    enc[(m0 + m) * BDD + n] = fmaxf(acc[m] + eb, 0.f);
}

// ---------- per-splat transform ----------
__global__ void k_trans(const float* __restrict__ enc, const float* __restrict__ trW,
                        const float* __restrict__ trB, float* __restrict__ trf) {
  __shared__ float red[2][8][128];
  int nq = blockIdx.x, ks = blockIdx.y;
  int nl = threadIdx.x & 127, dh = threadIdx.x >> 7;
  int n = nq * 128 + nl;
  float acc[8];
#pragma unroll
  for (int m = 0; m < 8; ++m) acc[m] = 0.f;
  for (int dq = 0; dq < 64; ++dq) {
    int d = dh * 256 + dq * 4;
    float w0 = trW[(ks * BDD + d + 0) * BDD + n];
    float w1 = trW[(ks * BDD + d + 1) * BDD + n];
    float w2 = trW[(ks * BDD + d + 2) * BDD + n];
    float w3 = trW[(ks * BDD + d + 3) * BDD + n];
#pragma unroll
    for (int m = 0; m < 8; ++m) {
      float4 e = *(const float4*)(enc + (m * NSP + ks) * BDD + d);
      acc[m] += e.x * w0 + e.y * w1 + e.z * w2 + e.w * w3;
    }
  }
#pragma unroll
  for (int m = 0; m < 8; ++m) red[dh][m][nl] = acc[m];
  __syncthreads();
  if (dh == 0) {
    float tb = trB[ks * BDD + n];
#pragma unroll
    for (int m = 0; m < 8; ++m)
      trf[(m * NSP + ks) * BDD + n] = red[0][m][nl] + red[1][m][nl] + tb;
  }
}

// ---------- decoder -> decT[b][n][ks] bf16 ----------
__global__ void k_dec(const float* __restrict__ trf, const float* __restrict__ decW,
                      const float* __restrict__ decB, u16* __restrict__ decT) {
  __shared__ u16 dt_lds[8][256];
  int nq = blockIdx.x, mt = blockIdx.y;
  int m0 = mt * 8;
  int n = nq * 256 + threadIdx.x;
  float acc[8];
#pragma unroll
  for (int m = 0; m < 8; ++m) acc[m] = 0.f;
  for (int dq = 0; dq < 128; ++dq) {
    int d = dq * 4;
    float w0 = decW[(d + 0) * DD + n];
    float w1 = decW[(d + 1) * DD + n];
    float w2 = decW[(d + 2) * DD + n];
    float w3 = decW[(d + 3) * DD + n];
#pragma unroll
    for (int m = 0; m < 8; ++m) {
      float4 x = *(const float4*)(trf + (m0 + m) * BDD + d);
      acc[m] += x.x * w0 + x.y * w1 + x.z * w2 + x.w * w3;
    }
  }
  float db = decB[n];
  int b = m0 >> 6, ks0 = m0 & 63;
#pragma unroll
  for (int m = 0; m < 8; ++m) dt_lds[m][threadIdx.x] = f2bf(acc[m] + db);
  __syncthreads();
  int j = threadIdx.x;
  uint4 v;
  v.x = dt_lds[0][j] | ((u32)dt_lds[1][j] << 16);
  v.y = dt_lds[2][j] | ((u32)dt_lds[3][j] << 16);
  v.z = dt_lds[4][j] | ((u32)dt_lds[5][j] << 16);
  v.w = dt_lds[6][j] | ((u32)dt_lds[7][j] << 16);
  *(uint4*)(decT + (b * DD + nq * 256 + j) * NSP + ks0) = v;
}

// ---------- fused gate GEMM (bf16 MFMA) + scatter MFMA + sigmoid*flow ----------
__global__ __launch_bounds__(256) void k_out(const u16* __restrict__ tokbf,
                                             const u16* __restrict__ gwt,
                                             const u16* __restrict__ inflbf,
                                             const u16* __restrict__ decT,
                                             const float* __restrict__ gateB,
                                             float* __restrict__ outp) {
  __shared__ u16 As[128 * 64];
  __shared__ u16 Bs[128 * 64];
  int t = threadIdx.x;
  int l = t & 63, w = t >> 6;
  int wr = w >> 1, wc = w & 1;
  int m0 = blockIdx.x * 128, n0 = blockIdx.y * 128;
  int l15 = l & 15, lh = l >> 4;
  int srow = t >> 3, scol = (t & 7) * 8;

  f32x4 accg[4][4];
#pragma unroll
  for (int i = 0; i < 4; ++i)
#pragma unroll
    for (int j = 0; j < 4; ++j) accg[i][j] = (f32x4){0.f, 0.f, 0.f, 0.f};

  for (int kt = 0; kt < 16; ++kt) {
    int k0 = kt * 64;
#pragma unroll
    for (int iss = 0; iss < 4; ++iss) {
      int row = iss * 32 + srow;
      gl_lds16(tokbf + (m0 + row) * DD + k0 + scol, &As[row * 64 + scol]);
      gl_lds16(gwt + (n0 + row) * DD + k0 + scol, &Bs[row * 64 + scol]);
    }
    __syncthreads();
#pragma unroll
    for (int ks = 0; ks < 2; ++ks) {
      bf16x8 af[4], bfv[4];
#pragma unroll
      for (int mi = 0; mi < 4; ++mi)
        af[mi] = *(const bf16x8*)&As[(wr * 64 + mi * 16 + l15) * 64 + ks * 32 + lh * 8];
#pragma unroll
      for (int ni = 0; ni < 4; ++ni)
        bfv[ni] = *(const bf16x8*)&Bs[(wc * 64 + ni * 16 + l15) * 64 + ks * 32 + lh * 8];
#pragma unroll
      for (int mi = 0; mi < 4; ++mi)
#pragma unroll
        for (int ni = 0; ni < 4; ++ni)
          accg[mi][ni] = __builtin_amdgcn_mfma_f32_16x16x32_bf16(af[mi], bfv[ni], accg[mi][ni], 0, 0, 0);
    }
    __syncthreads();
  }

  int b = m0 >> 11;
  int s0 = m0 & 2047;
#pragma unroll
  for (int iss = 0; iss < 4; ++iss) {
    int row = iss * 32 + srow;
    gl_lds16(inflbf + (b * SS + s0 + row) * NSP + scol, &As[row * 64 + scol]);
    gl_lds16(decT + (b * DD + n0 + row) * NSP + scol, &Bs[row * 64 + scol]);
  }
  __syncthreads();
  f32x4 accf[4][4];
#pragma unroll
  for (int i = 0; i < 4; ++i)
#pragma unroll
    for (int j = 0; j < 4; ++j) accf[i][j] = (f32x4){0.f, 0.f, 0.f, 0.f};
#pragma unroll
  for (int ks = 0; ks < 2; ++ks) {
    bf16x8 af[4], bfv[4];
#pragma unroll
    for (int mi = 0; mi < 4; ++mi)
      af[mi] = *(const bf16x8*)&As[(wr * 64 + mi * 16 + l15) * 64 + ks * 32 + lh * 8];
#pragma unroll
    for (int ni = 0; ni < 4; ++ni)
      bfv[ni] = *(const bf16x8*)&Bs[(wc * 64 + ni * 16 + l15) * 64 + ks * 32 + lh * 8];
#pragma unroll
    for (int mi = 0; mi < 4; ++mi)
#pragma unroll
      for (int ni = 0; ni < 4; ++ni)
        accf[mi][ni] = __builtin_amdgcn_mfma_f32_16x16x32_bf16(af[mi], bfv[ni], accf[mi][ni], 0, 0, 0);
  }

  float gb[4];
#pragma unroll
  for (int ni = 0; ni < 4; ++ni) gb[ni] = gateB[n0 + wc * 64 + ni * 16 + l15];
#pragma unroll
  for (int mi = 0; mi < 4; ++mi)
#pragma unroll
    for (int ni = 0; ni < 4; ++ni)
#pragma unroll
      for (int r = 0; r < 4; ++r) {
        int mr = m0 + wr * 64 + mi * 16 + lh * 4 + r;
        int nc = n0 + wc * 64 + ni * 16 + l15;
        float z = accg[mi][ni][r] + gb[ni];
        float gate = 1.f / (1.f + __expf(-z));
        outp[mr * DD + nc] = accf[mi][ni][r] * gate;
      }
}

extern "C" void kernel_launch(void* const* d_in, const int* in_sizes, int n_in,
                              void* d_out, int out_size, void* d_ws, size_t ws_size,
                              hipStream_t stream) {
  const float* tok = (const float*)d_in[0];
  const float* infl = (const float*)d_in[1];
  const float* encW = (const float*)d_in[2];
  const float* encB = (const float*)d_in[3];
  const float* trW = (const float*)d_in[4];
  const float* trB = (const float*)d_in[5];
  const float* decW = (const float*)d_in[6];
  const float* decB = (const float*)d_in[7];
  const float* gw = (const float*)d_in[8];
  const float* gateB = (const float*)d_in[9];
  float* outp = (float*)d_out;

  char* wsp = (char*)d_ws;
  u16* tokbf = (u16*)(wsp);                    // 33,554,432 B
  u16* gwt = (u16*)(wsp + 33554432);           //  2,097,152 B
  u16* inflbf = (u16*)(wsp + 35651584);        //  2,097,152 B
  float* rtot = (float*)(wsp + 37748736);      //      2,048 B
  float* gath = (float*)(wsp + 37750784);      //  2,097,152 B
  float* enc = (float*)(wsp + 39847936);       //  1,048,576 B
  float* trf = (float*)(wsp + 40896512);       //  1,048,576 B
  u16* decT = (u16*)(wsp + 41945088);          //  1,048,576 B
  u16* tokT = (u16*)(wsp + 42993664);          // 33,554,432 B
  u16* inflT = (u16*)(wsp + 76548096);         //  2,097,152 B  (end ~78.6 MB)

  k_cvt8<<<dim3(8192), dim3(256), 0, stream>>>(tok, tokbf);
  k_cvt8<<<dim3(512), dim3(256), 0, stream>>>(infl, inflbf);
  k_transpose<<<dim3(16, 256), dim3(256), 0, stream>>>(tokbf, tokT, DD);
  k_transpose<<<dim3(1, 256), dim3(256), 0, stream>>>(inflbf, inflT, NSP);
  k_gatewt<<<dim3(32, 32), dim3(256), 0, stream>>>(gw, gwt);
  k_tot<<<dim3(8), dim3(256), 0, stream>>>(infl, rtot);
  k_gather_mfma<<<dim3(16, 8), dim3(256), 0, stream>>>(inflT, tokT, rtot, gath);
  k_enc<<<dim3(2, 64), dim3(256), 0, stream>>>(gath, encW, encB, enc);
  k_trans<<<dim3(4, 64), dim3(256), 0, stream>>>(enc, trW, trB, trf);
  k_dec<<<dim3(4, 64), dim3(256), 0, stream>>>(trf, decW, decB, decT);
  k_out<<<dim3(128, 8), dim3(256), 0, stream>>>(tokbf, gwt, inflbf, decT, gateB, outp);
}

// Round 3
// 204.451 us; speedup vs baseline: 2.5552x; 1.7111x over previous
//
#include <hip/hip_runtime.h>

#define BB 8
#define SS 2048
#define DD 1024
#define BDD 512
#define NSP 64

typedef __attribute__((ext_vector_type(8))) short bf16x8;
typedef __attribute__((ext_vector_type(4))) float f32x4;
typedef unsigned short u16;
typedef unsigned int u32;

__device__ __forceinline__ u16 f2bf(float f) {
  u32 u = __builtin_bit_cast(u32, f);
  u = u + 0x7fffu + ((u >> 16) & 1u);
  return (u16)(u >> 16);
}

__device__ __forceinline__ void gl_lds16(const void* g, void* l) {
  __builtin_amdgcn_global_load_lds((const __attribute__((address_space(1))) void*)g,
                                   (__attribute__((address_space(3))) void*)l,
                                   16, 0, 0);
}

// ---------- convert 8 f32 -> 8 bf16 per thread ----------
__global__ void k_cvt8(const float* __restrict__ in, u16* __restrict__ outp) {
  int i = (blockIdx.x * 256 + threadIdx.x) * 8;
  float4 a = *(const float4*)(in + i);
  float4 b = *(const float4*)(in + i + 4);
  uint4 v;
  v.x = f2bf(a.x) | ((u32)f2bf(a.y) << 16);
  v.y = f2bf(a.z) | ((u32)f2bf(a.w) << 16);
  v.z = f2bf(b.x) | ((u32)f2bf(b.y) << 16);
  v.w = f2bf(b.z) | ((u32)f2bf(b.w) << 16);
  *(uint4*)(outp + i) = v;
}

// ---------- bf16 transpose: in [b*2048+s][W] -> out [b][W][2048] ----------
__global__ void k_transpose(const u16* __restrict__ in, u16* __restrict__ outp, int W) {
  __shared__ u16 tile[64][80];
  int C0 = blockIdx.x * 64;
  int R0 = blockIdx.y * 64;
  int b = R0 >> 11;
  int s0 = R0 & 2047;
  int t = threadIdx.x;
  int lr = t >> 3, lc = (t & 7) * 8;
#pragma unroll
  for (int i = 0; i < 2; ++i) {
    int r = lr + i * 32;
    uint4 v = *(const uint4*)(in + (R0 + r) * W + C0 + lc);
    *(uint4*)&tile[r][lc] = v;
  }
  __syncthreads();
  int sseg = (t & 7) * 8;
#pragma unroll
  for (int i = 0; i < 2; ++i) {
    int dcol = (t >> 3) + i * 32;
    u16 a0 = tile[sseg + 0][dcol], a1 = tile[sseg + 1][dcol];
    u16 a2 = tile[sseg + 2][dcol], a3 = tile[sseg + 3][dcol];
    u16 a4 = tile[sseg + 4][dcol], a5 = tile[sseg + 5][dcol];
    u16 a6 = tile[sseg + 6][dcol], a7 = tile[sseg + 7][dcol];
    uint4 v;
    v.x = a0 | ((u32)a1 << 16);
    v.y = a2 | ((u32)a3 << 16);
    v.z = a4 | ((u32)a5 << 16);
    v.w = a6 | ((u32)a7 << 16);
    *(uint4*)(outp + (size_t)b * W * SS + (size_t)(C0 + dcol) * SS + s0 + sseg) = v;
  }
}

// ---------- gate_W [k][n] f32 -> gwt [n][k] bf16 ----------
__global__ void k_gatewt(const float* __restrict__ gw, u16* __restrict__ gwt) {
  __shared__ float tile[32][33];
  int n0 = blockIdx.x * 32, k0 = blockIdx.y * 32;
  int tx = threadIdx.x & 31, ty = threadIdx.x >> 5;
#pragma unroll
  for (int r = 0; r < 4; ++r) {
    int kr = ty + r * 8;
    tile[kr][tx] = gw[(k0 + kr) * DD + n0 + tx];
  }
  __syncthreads();
#pragma unroll
  for (int r = 0; r < 4; ++r) {
    int nc = ty + r * 8;
    gwt[(n0 + nc) * DD + k0 + tx] = f2bf(tile[tx][nc]);
  }
}

// ---------- totals -> reciprocal ----------
__global__ void k_tot(const float* __restrict__ infl, float* __restrict__ rtot) {
  __shared__ float red[16][64];
  int b = blockIdx.x;
  int kq = threadIdx.x & 15, q = threadIdx.x >> 4;
  float a0 = 0.f, a1 = 0.f, a2 = 0.f, a3 = 0.f;
  for (int i = 0; i < 128; ++i) {
    int s = q * 128 + i;
    float4 v = *(const float4*)(infl + (b * SS + s) * NSP + kq * 4);
    a0 += v.x; a1 += v.y; a2 += v.z; a3 += v.w;
  }
  red[q][kq * 4 + 0] = a0;
  red[q][kq * 4 + 1] = a1;
  red[q][kq * 4 + 2] = a2;
  red[q][kq * 4 + 3] = a3;
  __syncthreads();
  if (threadIdx.x < 64) {
    float tt = 0.f;
#pragma unroll
    for (int qq = 0; qq < 16; ++qq) tt += red[qq][threadIdx.x];
    rtot[b * NSP + threadIdx.x] = 1.f / fmaxf(tt, 1e-8f);
  }
}

// ---------- MFMA gather partials: pg[sq][b*64+k][d] = sum_{s in sq} inflT*tokT ----------
// grid (16 dtile, 8 b, 4 sq), 256 threads
__global__ __launch_bounds__(256) void k_gather_mfma(const u16* __restrict__ inflT,
                                                     const u16* __restrict__ tokT,
                                                     float* __restrict__ pg) {
  __shared__ u16 As[64 * 64];
  __shared__ u16 Bs[64 * 64];
  int t = threadIdx.x;
  int l = t & 63, w = t >> 6;
  int wr = w >> 1, wc = w & 1;
  int n0 = blockIdx.x * 64;
  int b = blockIdx.y;
  int sq = blockIdx.z;
  int l15 = l & 15, lh = l >> 4;
  int srow = t >> 3, scol = (t & 7) * 8;

  const u16* ap = inflT + (size_t)b * NSP * SS;
  const u16* bp = tokT + (size_t)b * DD * SS;

  f32x4 acc[2][2];
#pragma unroll
  for (int i = 0; i < 2; ++i)
#pragma unroll
    for (int j = 0; j < 2; ++j) acc[i][j] = (f32x4){0.f, 0.f, 0.f, 0.f};

  for (int kt = 0; kt < 8; ++kt) {
    int k0 = sq * 512 + kt * 64;
#pragma unroll
    for (int i = 0; i < 2; ++i) {
      int row = srow + i * 32;
      gl_lds16(ap + row * SS + k0 + scol, &As[row * 64 + scol]);
      gl_lds16(bp + (n0 + row) * SS + k0 + scol, &Bs[row * 64 + scol]);
    }
    __syncthreads();
#pragma unroll
    for (int ks = 0; ks < 2; ++ks) {
      bf16x8 af[2], bfv[2];
#pragma unroll
      for (int mi = 0; mi < 2; ++mi)
        af[mi] = *(const bf16x8*)&As[(wr * 32 + mi * 16 + l15) * 64 + ks * 32 + lh * 8];
#pragma unroll
      for (int ni = 0; ni < 2; ++ni)
        bfv[ni] = *(const bf16x8*)&Bs[(wc * 32 + ni * 16 + l15) * 64 + ks * 32 + lh * 8];
#pragma unroll
      for (int mi = 0; mi < 2; ++mi)
#pragma unroll
        for (int ni = 0; ni < 2; ++ni)
          acc[mi][ni] = __builtin_amdgcn_mfma_f32_16x16x32_bf16(af[mi], bfv[ni], acc[mi][ni], 0, 0, 0);
    }
    __syncthreads();
  }

#pragma unroll
  for (int mi = 0; mi < 2; ++mi)
#pragma unroll
    for (int ni = 0; ni < 2; ++ni)
#pragma unroll
      for (int r = 0; r < 4; ++r) {
        int krow = wr * 32 + mi * 16 + lh * 4 + r;
        int dcol = n0 + wc * 32 + ni * 16 + l15;
        pg[((size_t)sq * 512 + b * NSP + krow) * DD + dcol] = acc[mi][ni][r];
      }
}

// ---------- reduce gather partials, apply rtot: gath[m][d] f32 ----------
// grid 512 (m), block 256
__global__ void red_gath(const float* __restrict__ pg, const float* __restrict__ rtot,
                         float* __restrict__ gath) {
  int m = blockIdx.x;
  int n4 = threadIdx.x * 4;
  float4 s = {0.f, 0.f, 0.f, 0.f};
#pragma unroll
  for (int q = 0; q < 4; ++q) {
    float4 v = *(const float4*)(pg + ((size_t)q * 512 + m) * DD + n4);
    s.x += v.x; s.y += v.y; s.z += v.z; s.w += v.w;
  }
  float rt = rtot[m];
  s.x *= rt; s.y *= rt; s.z *= rt; s.w *= rt;
  *(float4*)(gath + (size_t)m * DD + n4) = s;
}

// ---------- enc partials: pe[dq][m][n] = sum_{d in dq-slice} gath[m][d]*encW[d][n] ----------
// grid (16 dq, 64 mt), block 256
__global__ void k_enc_part(const float* __restrict__ gath, const float* __restrict__ encW,
                           float* __restrict__ pe) {
  __shared__ float gl[8][64];
  int dq = blockIdx.x, mt = blockIdx.y;
  int m0 = mt * 8, d0 = dq * 64;
  int t = threadIdx.x;
  {
    int r = t >> 5, c = t & 31;
    gl[r][c] = gath[(m0 + r) * DD + d0 + c];
    gl[r][c + 32] = gath[(m0 + r) * DD + d0 + c + 32];
  }
  __syncthreads();
  int n4 = (t & 127) * 4, mh = (t >> 7) * 4;
  float4 acc[4];
#pragma unroll
  for (int m = 0; m < 4; ++m) acc[m] = (float4){0.f, 0.f, 0.f, 0.f};
  for (int i = 0; i < 64; ++i) {
    float4 wv = *(const float4*)(encW + (d0 + i) * BDD + n4);
#pragma unroll
    for (int m = 0; m < 4; ++m) {
      float g = gl[mh + m][i];
      acc[m].x += g * wv.x; acc[m].y += g * wv.y;
      acc[m].z += g * wv.z; acc[m].w += g * wv.w;
    }
  }
#pragma unroll
  for (int m = 0; m < 4; ++m)
    *(float4*)(pe + ((size_t)dq * 512 + m0 + mh + m) * BDD + n4) = acc[m];
}

// ---------- reduce enc partials + bias + relu -> enc f32 [512][512] ----------
// grid 256, block 256
__global__ void red_enc(const float* __restrict__ pe, const float* __restrict__ encB,
                        float* __restrict__ enc) {
  int m = blockIdx.x * 2 + (threadIdx.x >> 7);
  int n4 = (threadIdx.x & 127) * 4;
  float4 s = {0.f, 0.f, 0.f, 0.f};
#pragma unroll
  for (int p = 0; p < 16; ++p) {
    float4 v = *(const float4*)(pe + ((size_t)p * 512 + m) * BDD + n4);
    s.x += v.x; s.y += v.y; s.z += v.z; s.w += v.w;
  }
  float4 bv = *(const float4*)(encB + n4);
  s.x = fmaxf(s.x + bv.x, 0.f); s.y = fmaxf(s.y + bv.y, 0.f);
  s.z = fmaxf(s.z + bv.z, 0.f); s.w = fmaxf(s.w + bv.w, 0.f);
  *(float4*)(enc + (size_t)m * BDD + n4) = s;
}

// ---------- trans partials: pt[dq][b*64+ks][e] over d-slice of 32 ----------
// grid (16 dq, 64 ks), block 256
__global__ void k_trans_part(const float* __restrict__ enc, const float* __restrict__ trW,
                             float* __restrict__ pt) {
  __shared__ float el[8][32];
  int dq = blockIdx.x, ks = blockIdx.y;
  int d0 = dq * 32;
  int t = threadIdx.x;
  {
    int r = t >> 5, c = t & 31;
    el[r][c] = enc[(r * NSP + ks) * BDD + d0 + c];
  }
  __syncthreads();
  int n4 = (t & 127) * 4, mh = (t >> 7) * 4;
  float4 acc[4];
#pragma unroll
  for (int m = 0; m < 4; ++m) acc[m] = (float4){0.f, 0.f, 0.f, 0.f};
  for (int i = 0; i < 32; ++i) {
    float4 wv = *(const float4*)(trW + ((size_t)ks * BDD + d0 + i) * BDD + n4);
#pragma unroll
    for (int m = 0; m < 4; ++m) {
      float g = el[mh + m][i];
      acc[m].x += g * wv.x; acc[m].y += g * wv.y;
      acc[m].z += g * wv.z; acc[m].w += g * wv.w;
    }
  }
#pragma unroll
  for (int m = 0; m < 4; ++m)
    *(float4*)(pt + ((size_t)dq * 512 + (mh + m) * NSP + ks) * BDD + n4) = acc[m];
}

// ---------- reduce trans partials + bias -> trf f32 [512][512] ----------
__global__ void red_trans(const float* __restrict__ pt, const float* __restrict__ trB,
                          float* __restrict__ trf) {
  int m = blockIdx.x * 2 + (threadIdx.x >> 7);
  int n4 = (threadIdx.x & 127) * 4;
  float4 s = {0.f, 0.f, 0.f, 0.f};
#pragma unroll
  for (int p = 0; p < 16; ++p) {
    float4 v = *(const float4*)(pt + ((size_t)p * 512 + m) * BDD + n4);
    s.x += v.x; s.y += v.y; s.z += v.z; s.w += v.w;
  }
  float4 bv = *(const float4*)(trB + (m & 63) * BDD + n4);
  s.x += bv.x; s.y += bv.y; s.z += bv.z; s.w += bv.w;
  *(float4*)(trf + (size_t)m * BDD + n4) = s;
}

// ---------- dec partials: pd[dq][m][n] over e-slice of 64 ----------
// grid (8 dq, 64 mt), block 256
__global__ void k_dec_part(const float* __restrict__ trf, const float* __restrict__ decW,
                           float* __restrict__ pd) {
  __shared__ float tl[8][64];
  int dq = blockIdx.x, mt = blockIdx.y;
  int m0 = mt * 8, d0 = dq * 64;
  int t = threadIdx.x;
  {
    int r = t >> 5, c = t & 31;
    tl[r][c] = trf[(m0 + r) * BDD + d0 + c];
    tl[r][c + 32] = trf[(m0 + r) * BDD + d0 + c + 32];
  }
  __syncthreads();
  int n4 = t * 4;
  float4 acc[8];
#pragma unroll
  for (int m = 0; m < 8; ++m) acc[m] = (float4){0.f, 0.f, 0.f, 0.f};
  for (int i = 0; i < 64; ++i) {
    float4 wv = *(const float4*)(decW + (d0 + i) * DD + n4);
#pragma unroll
    for (int m = 0; m < 8; ++m) {
      float g = tl[m][i];
      acc[m].x += g * wv.x; acc[m].y += g * wv.y;
      acc[m].z += g * wv.z; acc[m].w += g * wv.w;
    }
  }
#pragma unroll
  for (int m = 0; m < 8; ++m)
    *(float4*)(pd + ((size_t)dq * 512 + m0 + m) * DD + n4) = acc[m];
}

// ---------- reduce dec partials + bias -> decT[b][n][ks] bf16 ----------
// grid (32 nt, 8 b), block 256
__global__ void red_dec(const float* __restrict__ pd, const float* __restrict__ decB,
                        u16* __restrict__ decT) {
  __shared__ u16 st[64][34];
  int nt = blockIdx.x, b = blockIdx.y;
  int n0 = nt * 32;
  int t = threadIdx.x;
  int nn = t & 31, kg = t >> 5;
  float db = decB[n0 + nn];
#pragma unroll
  for (int ki = 0; ki < 8; ++ki) {
    int ks = kg * 8 + ki;
    float s = db;
#pragma unroll
    for (int p = 0; p < 8; ++p)
      s += pd[((size_t)p * 512 + b * NSP + ks) * DD + n0 + nn];
    st[ks][nn] = f2bf(s);
  }
  __syncthreads();
  int nr = t >> 3, kseg = (t & 7) * 8;
  uint4 v;
  v.x = st[kseg + 0][nr] | ((u32)st[kseg + 1][nr] << 16);
  v.y = st[kseg + 2][nr] | ((u32)st[kseg + 3][nr] << 16);
  v.z = st[kseg + 4][nr] | ((u32)st[kseg + 5][nr] << 16);
  v.w = st[kseg + 6][nr] | ((u32)st[kseg + 7][nr] << 16);
  *(uint4*)(decT + ((size_t)b * DD + n0 + nr) * NSP + kseg) = v;
}

// ---------- fused gate GEMM (bf16 MFMA) + scatter MFMA + sigmoid*flow ----------
__global__ __launch_bounds__(256) void k_out(const u16* __restrict__ tokbf,
                                             const u16* __restrict__ gwt,
                                             const u16* __restrict__ inflbf,
                                             const u16* __restrict__ decT,
                                             const float* __restrict__ gateB,
                                             float* __restrict__ outp) {
  __shared__ u16 As[128 * 64];
  __shared__ u16 Bs[128 * 64];
  int t = threadIdx.x;
  int l = t & 63, w = t >> 6;
  int wr = w >> 1, wc = w & 1;
  int m0 = blockIdx.x * 128, n0 = blockIdx.y * 128;
  int l15 = l & 15, lh = l >> 4;
  int srow = t >> 3, scol = (t & 7) * 8;

  f32x4 accg[4][4];
#pragma unroll
  for (int i = 0; i < 4; ++i)
#pragma unroll
    for (int j = 0; j < 4; ++j) accg[i][j] = (f32x4){0.f, 0.f, 0.f, 0.f};

  for (int kt = 0; kt < 16; ++kt) {
    int k0 = kt * 64;
#pragma unroll
    for (int iss = 0; iss < 4; ++iss) {
      int row = iss * 32 + srow;
      gl_lds16(tokbf + (m0 + row) * DD + k0 + scol, &As[row * 64 + scol]);
      gl_lds16(gwt + (n0 + row) * DD + k0 + scol, &Bs[row * 64 + scol]);
    }
    __syncthreads();
#pragma unroll
    for (int ks = 0; ks < 2; ++ks) {
      bf16x8 af[4], bfv[4];
#pragma unroll
      for (int mi = 0; mi < 4; ++mi)
        af[mi] = *(const bf16x8*)&As[(wr * 64 + mi * 16 + l15) * 64 + ks * 32 + lh * 8];
#pragma unroll
      for (int ni = 0; ni < 4; ++ni)
        bfv[ni] = *(const bf16x8*)&Bs[(wc * 64 + ni * 16 + l15) * 64 + ks * 32 + lh * 8];
#pragma unroll
      for (int mi = 0; mi < 4; ++mi)
#pragma unroll
        for (int ni = 0; ni < 4; ++ni)
          accg[mi][ni] = __builtin_amdgcn_mfma_f32_16x16x32_bf16(af[mi], bfv[ni], accg[mi][ni], 0, 0, 0);
    }
    __syncthreads();
  }

  int b = m0 >> 11;
  int s0 = m0 & 2047;
#pragma unroll
  for (int iss = 0; iss < 4; ++iss) {
    int row = iss * 32 + srow;
    gl_lds16(inflbf + (b * SS + s0 + row) * NSP + scol, &As[row * 64 + scol]);
    gl_lds16(decT + (b * DD + n0 + row) * NSP + scol, &Bs[row * 64 + scol]);
  }
  __syncthreads();
  f32x4 accf[4][4];
#pragma unroll
  for (int i = 0; i < 4; ++i)
#pragma unroll
    for (int j = 0; j < 4; ++j) accf[i][j] = (f32x4){0.f, 0.f, 0.f, 0.f};
#pragma unroll
  for (int ks = 0; ks < 2; ++ks) {
    bf16x8 af[4], bfv[4];
#pragma unroll
    for (int mi = 0; mi < 4; ++mi)
      af[mi] = *(const bf16x8*)&As[(wr * 64 + mi * 16 + l15) * 64 + ks * 32 + lh * 8];
#pragma unroll
    for (int ni = 0; ni < 4; ++ni)
      bfv[ni] = *(const bf16x8*)&Bs[(wc * 64 + ni * 16 + l15) * 64 + ks * 32 + lh * 8];
#pragma unroll
    for (int mi = 0; mi < 4; ++mi)
#pragma unroll
      for (int ni = 0; ni < 4; ++ni)
        accf[mi][ni] = __builtin_amdgcn_mfma_f32_16x16x32_bf16(af[mi], bfv[ni], accf[mi][ni], 0, 0, 0);
  }

  float gb[4];
#pragma unroll
  for (int ni = 0; ni < 4; ++ni) gb[ni] = gateB[n0 + wc * 64 + ni * 16 + l15];
#pragma unroll
  for (int mi = 0; mi < 4; ++mi)
#pragma unroll
    for (int ni = 0; ni < 4; ++ni)
#pragma unroll
      for (int r = 0; r < 4; ++r) {
        int mr = m0 + wr * 64 + mi * 16 + lh * 4 + r;
        int nc = n0 + wc * 64 + ni * 16 + l15;
        float z = accg[mi][ni][r] + gb[ni];
        float gate = 1.f / (1.f + __expf(-z));
        outp[mr * DD + nc] = accf[mi][ni][r] * gate;
      }
}

extern "C" void kernel_launch(void* const* d_in, const int* in_sizes, int n_in,
                              void* d_out, int out_size, void* d_ws, size_t ws_size,
                              hipStream_t stream) {
  const float* tok = (const float*)d_in[0];
  const float* infl = (const float*)d_in[1];
  const float* encW = (const float*)d_in[2];
  const float* encB = (const float*)d_in[3];
  const float* trW = (const float*)d_in[4];
  const float* trB = (const float*)d_in[5];
  const float* decW = (const float*)d_in[6];
  const float* decB = (const float*)d_in[7];
  const float* gw = (const float*)d_in[8];
  const float* gateB = (const float*)d_in[9];
  float* outp = (float*)d_out;

  char* wsp = (char*)d_ws;
  u16* tokbf = (u16*)(wsp);                    // 33,554,432 B
  u16* gwt = (u16*)(wsp + 33554432);           //  2,097,152 B
  u16* inflbf = (u16*)(wsp + 35651584);        //  2,097,152 B
  float* rtot = (float*)(wsp + 37748736);      //      2,048 B
  float* gath = (float*)(wsp + 37750784);      //  2,097,152 B
  float* enc = (float*)(wsp + 39847936);       //  1,048,576 B
  float* trf = (float*)(wsp + 40896512);       //  1,048,576 B
  u16* decT = (u16*)(wsp + 41945088);          //  1,048,576 B
  u16* tokT = (u16*)(wsp + 42993664);          // 33,554,432 B
  u16* inflT = (u16*)(wsp + 76548096);         //  2,097,152 B
  float* scratch = (float*)(wsp + 78645248);   // 16,777,216 B shared: pg/pe/pt/pd (end ~91 MB)

  k_cvt8<<<dim3(8192), dim3(256), 0, stream>>>(tok, tokbf);
  k_cvt8<<<dim3(512), dim3(256), 0, stream>>>(infl, inflbf);
  k_transpose<<<dim3(16, 256), dim3(256), 0, stream>>>(tokbf, tokT, DD);
  k_transpose<<<dim3(1, 256), dim3(256), 0, stream>>>(inflbf, inflT, NSP);
  k_gatewt<<<dim3(32, 32), dim3(256), 0, stream>>>(gw, gwt);
  k_tot<<<dim3(8), dim3(256), 0, stream>>>(infl, rtot);
  k_gather_mfma<<<dim3(16, 8, 4), dim3(256), 0, stream>>>(inflT, tokT, scratch);
  red_gath<<<dim3(512), dim3(256), 0, stream>>>(scratch, rtot, gath);
  k_enc_part<<<dim3(16, 64), dim3(256), 0, stream>>>(gath, encW, scratch);
  red_enc<<<dim3(256), dim3(256), 0, stream>>>(scratch, encB, enc);
  k_trans_part<<<dim3(16, 64), dim3(256), 0, stream>>>(enc, trW, scratch);
  red_trans<<<dim3(256), dim3(256), 0, stream>>>(scratch, trB, trf);
  k_dec_part<<<dim3(8, 64), dim3(256), 0, stream>>>(trf, decW, scratch);
  red_dec<<<dim3(32, 8), dim3(256), 0, stream>>>(scratch, decB, decT);
  k_out<<<dim3(128, 8), dim3(256), 0, stream>>>(tokbf, gwt, inflbf, decT, gateB, outp);
}

// Round 4
// 186.384 us; speedup vs baseline: 2.8029x; 1.0969x over previous
//
#include <hip/hip_runtime.h>

#define BB 8
#define SS 2048
#define DD 1024
#define BDD 512
#define NSP 64

typedef __attribute__((ext_vector_type(8))) short bf16x8;
typedef __attribute__((ext_vector_type(4))) float f32x4;
typedef unsigned short u16;
typedef unsigned int u32;

__device__ __forceinline__ u16 f2bf(float f) {
  u32 u = __builtin_bit_cast(u32, f);
  u = u + 0x7fffu + ((u >> 16) & 1u);
  return (u16)(u >> 16);
}

__device__ __forceinline__ void gl_lds16(const void* g, void* l) {
  __builtin_amdgcn_global_load_lds((const __attribute__((address_space(1))) void*)g,
                                   (__attribute__((address_space(3))) void*)l,
                                   16, 0, 0);
}

// ---------- fused: tok f32 -> tokbf (bf16, row-major) + tokT (bf16, [b][d][s]) ----------
// grid (16, 256), block 256
__global__ void k_prep_tok(const float* __restrict__ tok, u16* __restrict__ tokbf,
                           u16* __restrict__ tokT) {
  __shared__ u16 tile[64][80];
  int C0 = blockIdx.x * 64;
  int R0 = blockIdx.y * 64;
  int b = R0 >> 11, s0 = R0 & 2047;
  int t = threadIdx.x;
  int lr = t >> 3, lc = (t & 7) * 8;
#pragma unroll
  for (int i = 0; i < 2; ++i) {
    int r = lr + i * 32;
    const float* src = tok + (size_t)(R0 + r) * DD + C0 + lc;
    float4 a = *(const float4*)src;
    float4 bq = *(const float4*)(src + 4);
    uint4 v;
    v.x = f2bf(a.x) | ((u32)f2bf(a.y) << 16);
    v.y = f2bf(a.z) | ((u32)f2bf(a.w) << 16);
    v.z = f2bf(bq.x) | ((u32)f2bf(bq.y) << 16);
    v.w = f2bf(bq.z) | ((u32)f2bf(bq.w) << 16);
    *(uint4*)(tokbf + (size_t)(R0 + r) * DD + C0 + lc) = v;
    *(uint4*)&tile[r][lc] = v;
  }
  __syncthreads();
  int sseg = (t & 7) * 8;
#pragma unroll
  for (int i = 0; i < 2; ++i) {
    int dcol = (t >> 3) + i * 32;
    u16 a0 = tile[sseg + 0][dcol], a1 = tile[sseg + 1][dcol];
    u16 a2 = tile[sseg + 2][dcol], a3 = tile[sseg + 3][dcol];
    u16 a4 = tile[sseg + 4][dcol], a5 = tile[sseg + 5][dcol];
    u16 a6 = tile[sseg + 6][dcol], a7 = tile[sseg + 7][dcol];
    uint4 v;
    v.x = a0 | ((u32)a1 << 16);
    v.y = a2 | ((u32)a3 << 16);
    v.z = a4 | ((u32)a5 << 16);
    v.w = a6 | ((u32)a7 << 16);
    *(uint4*)(tokT + (size_t)b * DD * SS + (size_t)(C0 + dcol) * SS + s0 + sseg) = v;
  }
}

// ---------- fused: infl f32 -> inflbf + inflT + per-tile column sums ----------
// grid 256, block 256
__global__ void k_prep_infl(const float* __restrict__ infl, u16* __restrict__ inflbf,
                            u16* __restrict__ inflT, float* __restrict__ rsum) {
  __shared__ u16 tile[64][80];
  __shared__ float ps[32][64];
  int R0 = blockIdx.x * 64;
  int b = R0 >> 11, s0 = R0 & 2047;
  int st = s0 >> 6;
  int t = threadIdx.x;
  int lr = t >> 3, lc = (t & 7) * 8;
  float col[8];
#pragma unroll
  for (int j = 0; j < 8; ++j) col[j] = 0.f;
#pragma unroll
  for (int i = 0; i < 2; ++i) {
    int r = lr + i * 32;
    const float* src = infl + (size_t)(R0 + r) * NSP + lc;
    float4 a = *(const float4*)src;
    float4 bq = *(const float4*)(src + 4);
    col[0] += a.x; col[1] += a.y; col[2] += a.z; col[3] += a.w;
    col[4] += bq.x; col[5] += bq.y; col[6] += bq.z; col[7] += bq.w;
    uint4 v;
    v.x = f2bf(a.x) | ((u32)f2bf(a.y) << 16);
    v.y = f2bf(a.z) | ((u32)f2bf(a.w) << 16);
    v.z = f2bf(bq.x) | ((u32)f2bf(bq.y) << 16);
    v.w = f2bf(bq.z) | ((u32)f2bf(bq.w) << 16);
    *(uint4*)(inflbf + (size_t)(R0 + r) * NSP + lc) = v;
    *(uint4*)&tile[r][lc] = v;
  }
#pragma unroll
  for (int j = 0; j < 8; ++j) ps[lr][lc + j] = col[j];
  __syncthreads();
  if (t < 64) {
    float s = 0.f;
#pragma unroll
    for (int rr = 0; rr < 32; ++rr) s += ps[rr][t];
    rsum[((size_t)b * 32 + st) * 64 + t] = s;
  }
  int sseg = (t & 7) * 8;
#pragma unroll
  for (int i = 0; i < 2; ++i) {
    int dcol = (t >> 3) + i * 32;
    u16 a0 = tile[sseg + 0][dcol], a1 = tile[sseg + 1][dcol];
    u16 a2 = tile[sseg + 2][dcol], a3 = tile[sseg + 3][dcol];
    u16 a4 = tile[sseg + 4][dcol], a5 = tile[sseg + 5][dcol];
    u16 a6 = tile[sseg + 6][dcol], a7 = tile[sseg + 7][dcol];
    uint4 v;
    v.x = a0 | ((u32)a1 << 16);
    v.y = a2 | ((u32)a3 << 16);
    v.z = a4 | ((u32)a5 << 16);
    v.w = a6 | ((u32)a7 << 16);
    *(uint4*)(inflT + ((size_t)b * NSP + dcol) * SS + s0 + sseg) = v;
  }
}

// ---------- finalize totals -> reciprocal ----------
__global__ void k_tot_fin(const float* __restrict__ rsum, float* __restrict__ rtot) {
  int t = threadIdx.x;  // 512 = 8b x 64k
  float s = 0.f;
#pragma unroll
  for (int st = 0; st < 32; ++st)
    s += rsum[((size_t)(t >> 6) * 32 + st) * 64 + (t & 63)];
  rtot[t] = 1.f / fmaxf(s, 1e-8f);
}

// ---------- gate_W [k][n] f32 -> gwt [n][k] bf16 ----------
__global__ void k_gatewt(const float* __restrict__ gw, u16* __restrict__ gwt) {
  __shared__ float tile[32][33];
  int n0 = blockIdx.x * 32, k0 = blockIdx.y * 32;
  int tx = threadIdx.x & 31, ty = threadIdx.x >> 5;
#pragma unroll
  for (int r = 0; r < 4; ++r) {
    int kr = ty + r * 8;
    tile[kr][tx] = gw[(k0 + kr) * DD + n0 + tx];
  }
  __syncthreads();
#pragma unroll
  for (int r = 0; r < 4; ++r) {
    int nc = ty + r * 8;
    gwt[(n0 + nc) * DD + k0 + tx] = f2bf(tile[tx][nc]);
  }
}

// ---------- MFMA gather partials ----------
// grid (16 dtile, 8 b, 4 sq), 256 threads
__global__ __launch_bounds__(256) void k_gather_mfma(const u16* __restrict__ inflT,
                                                     const u16* __restrict__ tokT,
                                                     float* __restrict__ pg) {
  __shared__ u16 As[64 * 64];
  __shared__ u16 Bs[64 * 64];
  int t = threadIdx.x;
  int l = t & 63, w = t >> 6;
  int wr = w >> 1, wc = w & 1;
  int n0 = blockIdx.x * 64;
  int b = blockIdx.y;
  int sq = blockIdx.z;
  int l15 = l & 15, lh = l >> 4;
  int srow = t >> 3, scol = (t & 7) * 8;

  const u16* ap = inflT + (size_t)b * NSP * SS;
  const u16* bp = tokT + (size_t)b * DD * SS;

  f32x4 acc[2][2];
#pragma unroll
  for (int i = 0; i < 2; ++i)
#pragma unroll
    for (int j = 0; j < 2; ++j) acc[i][j] = (f32x4){0.f, 0.f, 0.f, 0.f};

  for (int kt = 0; kt < 8; ++kt) {
    int k0 = sq * 512 + kt * 64;
#pragma unroll
    for (int i = 0; i < 2; ++i) {
      int row = srow + i * 32;
      gl_lds16(ap + row * SS + k0 + scol, &As[row * 64 + scol]);
      gl_lds16(bp + (n0 + row) * SS + k0 + scol, &Bs[row * 64 + scol]);
    }
    __syncthreads();
#pragma unroll
    for (int ks = 0; ks < 2; ++ks) {
      bf16x8 af[2], bfv[2];
#pragma unroll
      for (int mi = 0; mi < 2; ++mi)
        af[mi] = *(const bf16x8*)&As[(wr * 32 + mi * 16 + l15) * 64 + ks * 32 + lh * 8];
#pragma unroll
      for (int ni = 0; ni < 2; ++ni)
        bfv[ni] = *(const bf16x8*)&Bs[(wc * 32 + ni * 16 + l15) * 64 + ks * 32 + lh * 8];
#pragma unroll
      for (int mi = 0; mi < 2; ++mi)
#pragma unroll
        for (int ni = 0; ni < 2; ++ni)
          acc[mi][ni] = __builtin_amdgcn_mfma_f32_16x16x32_bf16(af[mi], bfv[ni], acc[mi][ni], 0, 0, 0);
    }
    __syncthreads();
  }

#pragma unroll
  for (int mi = 0; mi < 2; ++mi)
#pragma unroll
    for (int ni = 0; ni < 2; ++ni)
#pragma unroll
      for (int r = 0; r < 4; ++r) {
        int krow = wr * 32 + mi * 16 + lh * 4 + r;
        int dcol = n0 + wc * 32 + ni * 16 + l15;
        pg[((size_t)sq * 512 + b * NSP + krow) * DD + dcol] = acc[mi][ni][r];
      }
}

// ---------- reduce gather partials, apply rtot ----------
__global__ void red_gath(const float* __restrict__ pg, const float* __restrict__ rtot,
                         float* __restrict__ gath) {
  int m = blockIdx.x;
  int n4 = threadIdx.x * 4;
  float4 s = {0.f, 0.f, 0.f, 0.f};
#pragma unroll
  for (int q = 0; q < 4; ++q) {
    float4 v = *(const float4*)(pg + ((size_t)q * 512 + m) * DD + n4);
    s.x += v.x; s.y += v.y; s.z += v.z; s.w += v.w;
  }
  float rt = rtot[m];
  s.x *= rt; s.y *= rt; s.z *= rt; s.w *= rt;
  *(float4*)(gath + (size_t)m * DD + n4) = s;
}

// ---------- enc partials ----------
__global__ void k_enc_part(const float* __restrict__ gath, const float* __restrict__ encW,
                           float* __restrict__ pe) {
  __shared__ float gl[8][64];
  int dq = blockIdx.x, mt = blockIdx.y;
  int m0 = mt * 8, d0 = dq * 64;
  int t = threadIdx.x;
  {
    int r = t >> 5, c = t & 31;
    gl[r][c] = gath[(m0 + r) * DD + d0 + c];
    gl[r][c + 32] = gath[(m0 + r) * DD + d0 + c + 32];
  }
  __syncthreads();
  int n4 = (t & 127) * 4, mh = (t >> 7) * 4;
  float4 acc[4];
#pragma unroll
  for (int m = 0; m < 4; ++m) acc[m] = (float4){0.f, 0.f, 0.f, 0.f};
  for (int i = 0; i < 64; ++i) {
    float4 wv = *(const float4*)(encW + (d0 + i) * BDD + n4);
#pragma unroll
    for (int m = 0; m < 4; ++m) {
      float g = gl[mh + m][i];
      acc[m].x += g * wv.x; acc[m].y += g * wv.y;
      acc[m].z += g * wv.z; acc[m].w += g * wv.w;
    }
  }
#pragma unroll
  for (int m = 0; m < 4; ++m)
    *(float4*)(pe + ((size_t)dq * 512 + m0 + mh + m) * BDD + n4) = acc[m];
}

// ---------- reduce enc partials + bias + relu ----------
__global__ void red_enc(const float* __restrict__ pe, const float* __restrict__ encB,
                        float* __restrict__ enc) {
  int m = blockIdx.x * 2 + (threadIdx.x >> 7);
  int n4 = (threadIdx.x & 127) * 4;
  float4 s = {0.f, 0.f, 0.f, 0.f};
#pragma unroll
  for (int p = 0; p < 16; ++p) {
    float4 v = *(const float4*)(pe + ((size_t)p * 512 + m) * BDD + n4);
    s.x += v.x; s.y += v.y; s.z += v.z; s.w += v.w;
  }
  float4 bv = *(const float4*)(encB + n4);
  s.x = fmaxf(s.x + bv.x, 0.f); s.y = fmaxf(s.y + bv.y, 0.f);
  s.z = fmaxf(s.z + bv.z, 0.f); s.w = fmaxf(s.w + bv.w, 0.f);
  *(float4*)(enc + (size_t)m * BDD + n4) = s;
}

// ---------- trans partials ----------
__global__ void k_trans_part(const float* __restrict__ enc, const float* __restrict__ trW,
                             float* __restrict__ pt) {
  __shared__ float el[8][32];
  int dq = blockIdx.x, ks = blockIdx.y;
  int d0 = dq * 32;
  int t = threadIdx.x;
  {
    int r = t >> 5, c = t & 31;
    el[r][c] = enc[(r * NSP + ks) * BDD + d0 + c];
  }
  __syncthreads();
  int n4 = (t & 127) * 4, mh = (t >> 7) * 4;
  float4 acc[4];
#pragma unroll
  for (int m = 0; m < 4; ++m) acc[m] = (float4){0.f, 0.f, 0.f, 0.f};
  for (int i = 0; i < 32; ++i) {
    float4 wv = *(const float4*)(trW + ((size_t)ks * BDD + d0 + i) * BDD + n4);
#pragma unroll
    for (int m = 0; m < 4; ++m) {
      float g = el[mh + m][i];
      acc[m].x += g * wv.x; acc[m].y += g * wv.y;
      acc[m].z += g * wv.z; acc[m].w += g * wv.w;
    }
  }
#pragma unroll
  for (int m = 0; m < 4; ++m)
    *(float4*)(pt + ((size_t)dq * 512 + (mh + m) * NSP + ks) * BDD + n4) = acc[m];
}

// ---------- reduce trans partials + bias ----------
__global__ void red_trans(const float* __restrict__ pt, const float* __restrict__ trB,
                          float* __restrict__ trf) {
  int m = blockIdx.x * 2 + (threadIdx.x >> 7);
  int n4 = (threadIdx.x & 127) * 4;
  float4 s = {0.f, 0.f, 0.f, 0.f};
#pragma unroll
  for (int p = 0; p < 16; ++p) {
    float4 v = *(const float4*)(pt + ((size_t)p * 512 + m) * BDD + n4);
    s.x += v.x; s.y += v.y; s.z += v.z; s.w += v.w;
  }
  float4 bv = *(const float4*)(trB + (m & 63) * BDD + n4);
  s.x += bv.x; s.y += bv.y; s.z += bv.z; s.w += bv.w;
  *(float4*)(trf + (size_t)m * BDD + n4) = s;
}

// ---------- dec partials ----------
__global__ void k_dec_part(const float* __restrict__ trf, const float* __restrict__ decW,
                           float* __restrict__ pd) {
  __shared__ float tl[8][64];
  int dq = blockIdx.x, mt = blockIdx.y;
  int m0 = mt * 8, d0 = dq * 64;
  int t = threadIdx.x;
  {
    int r = t >> 5, c = t & 31;
    tl[r][c] = trf[(m0 + r) * BDD + d0 + c];
    tl[r][c + 32] = trf[(m0 + r) * BDD + d0 + c + 32];
  }
  __syncthreads();
  int n4 = t * 4;
  float4 acc[8];
#pragma unroll
  for (int m = 0; m < 8; ++m) acc[m] = (float4){0.f, 0.f, 0.f, 0.f};
  for (int i = 0; i < 64; ++i) {
    float4 wv = *(const float4*)(decW + (d0 + i) * DD + n4);
#pragma unroll
    for (int m = 0; m < 8; ++m) {
      float g = tl[m][i];
      acc[m].x += g * wv.x; acc[m].y += g * wv.y;
      acc[m].z += g * wv.z; acc[m].w += g * wv.w;
    }
  }
#pragma unroll
  for (int m = 0; m < 8; ++m)
    *(float4*)(pd + ((size_t)dq * 512 + m0 + m) * DD + n4) = acc[m];
}

// ---------- reduce dec partials + bias -> decT[b][n][ks] bf16 ----------
__global__ void red_dec(const float* __restrict__ pd, const float* __restrict__ decB,
                        u16* __restrict__ decT) {
  __shared__ u16 st[64][34];
  int nt = blockIdx.x, b = blockIdx.y;
  int n0 = nt * 32;
  int t = threadIdx.x;
  int nn = t & 31, kg = t >> 5;
  float db = decB[n0 + nn];
#pragma unroll
  for (int ki = 0; ki < 8; ++ki) {
    int ks = kg * 8 + ki;
    float s = db;
#pragma unroll
    for (int p = 0; p < 8; ++p)
      s += pd[((size_t)p * 512 + b * NSP + ks) * DD + n0 + nn];
    st[ks][nn] = f2bf(s);
  }
  __syncthreads();
  int nr = t >> 3, kseg = (t & 7) * 8;
  uint4 v;
  v.x = st[kseg + 0][nr] | ((u32)st[kseg + 1][nr] << 16);
  v.y = st[kseg + 2][nr] | ((u32)st[kseg + 3][nr] << 16);
  v.z = st[kseg + 4][nr] | ((u32)st[kseg + 5][nr] << 16);
  v.w = st[kseg + 6][nr] | ((u32)st[kseg + 7][nr] << 16);
  *(uint4*)(decT + ((size_t)b * DD + n0 + nr) * NSP + kseg) = v;
}

// ---------- fused gate GEMM + scatter MFMA + sigmoid*flow ----------
// BM=128, BN=256, BK=64; 512 threads (8 waves, 2x4); dbuf LDS; swizzled staging.
// grid (128 m-tiles, 4 n-tiles)
__global__ __launch_bounds__(512, 2) void k_out(const u16* __restrict__ tokbf,
                                                const u16* __restrict__ gwt,
                                                const u16* __restrict__ inflbf,
                                                const u16* __restrict__ decT,
                                                const float* __restrict__ gateB,
                                                float* __restrict__ outp) {
  __shared__ u16 As[2][128 * 64];
  __shared__ u16 Bs[2][256 * 64];
  int t = threadIdx.x;
  int l = t & 63, w = t >> 6;
  int wr = w >> 2, wc = w & 3;  // 2 x 4 wave grid, 64x64 per wave
  int m0 = blockIdx.x * 128, n0 = blockIdx.y * 256;
  int l15 = l & 15, lh = l >> 4;

  f32x4 accg[4][4];
#pragma unroll
  for (int i = 0; i < 4; ++i)
#pragma unroll
    for (int j = 0; j < 4; ++j) accg[i][j] = (f32x4){0.f, 0.f, 0.f, 0.f};

  // prologue stage kt=0 -> buf0 (LDS dest linear, source chunk-swizzled: rule-21 pattern)
#pragma unroll
  for (int p = 0; p < 2; ++p) {
    int e = p * 512 + t;
    int row = e >> 3, csrc = ((e & 7) ^ (row & 7)) * 8;
    gl_lds16(tokbf + (size_t)(m0 + row) * DD + csrc, &As[0][e * 8]);
  }
#pragma unroll
  for (int p = 0; p < 4; ++p) {
    int e = p * 512 + t;
    int row = e >> 3, csrc = ((e & 7) ^ (row & 7)) * 8;
    gl_lds16(gwt + (size_t)(n0 + row) * DD + csrc, &Bs[0][e * 8]);
  }
  asm volatile("s_waitcnt vmcnt(0)" ::: "memory");
  __builtin_amdgcn_s_barrier();

  for (int kt = 0; kt < 16; ++kt) {
    int cur = kt & 1;
    if (kt < 15) {
      int k0 = (kt + 1) * 64;
#pragma unroll
      for (int p = 0; p < 2; ++p) {
        int e = p * 512 + t;
        int row = e >> 3, csrc = ((e & 7) ^ (row & 7)) * 8;
        gl_lds16(tokbf + (size_t)(m0 + row) * DD + k0 + csrc, &As[cur ^ 1][e * 8]);
      }
#pragma unroll
      for (int p = 0; p < 4; ++p) {
        int e = p * 512 + t;
        int row = e >> 3, csrc = ((e & 7) ^ (row & 7)) * 8;
        gl_lds16(gwt + (size_t)(n0 + row) * DD + k0 + csrc, &Bs[cur ^ 1][e * 8]);
      }
    }
#pragma unroll
    for (int ks = 0; ks < 2; ++ks) {
      bf16x8 af[4], bfv[4];
      int g = ks * 4 + lh;
#pragma unroll
      for (int mi = 0; mi < 4; ++mi) {
        int r = wr * 64 + mi * 16 + l15;
        af[mi] = *(const bf16x8*)&As[cur][r * 64 + (g ^ (r & 7)) * 8];
      }
#pragma unroll
      for (int ni = 0; ni < 4; ++ni) {
        int r = wc * 64 + ni * 16 + l15;
        bfv[ni] = *(const bf16x8*)&Bs[cur][r * 64 + (g ^ (r & 7)) * 8];
      }
#pragma unroll
      for (int mi = 0; mi < 4; ++mi)
#pragma unroll
        for (int ni = 0; ni < 4; ++ni)
          accg[mi][ni] = __builtin_amdgcn_mfma_f32_16x16x32_bf16(af[mi], bfv[ni], accg[mi][ni], 0, 0, 0);
    }
    asm volatile("s_waitcnt vmcnt(0)" ::: "memory");
    __builtin_amdgcn_s_barrier();
  }

  // scatter pass: K = 64 splats, stage into buf0
  int b = m0 >> 11;
  int s0m = m0 & 2047;
#pragma unroll
  for (int p = 0; p < 2; ++p) {
    int e = p * 512 + t;
    int row = e >> 3, csrc = ((e & 7) ^ (row & 7)) * 8;
    gl_lds16(inflbf + ((size_t)b * SS + s0m + row) * NSP + csrc, &As[0][e * 8]);
  }
#pragma unroll
  for (int p = 0; p < 4; ++p) {
    int e = p * 512 + t;
    int row = e >> 3, csrc = ((e & 7) ^ (row & 7)) * 8;
    gl_lds16(decT + ((size_t)b * DD + n0 + row) * NSP + csrc, &Bs[0][e * 8]);
  }
  asm volatile("s_waitcnt vmcnt(0)" ::: "memory");
  __builtin_amdgcn_s_barrier();

  f32x4 accf[4][4];
#pragma unroll
  for (int i = 0; i < 4; ++i)
#pragma unroll
    for (int j = 0; j < 4; ++j) accf[i][j] = (f32x4){0.f, 0.f, 0.f, 0.f};
#pragma unroll
  for (int ks = 0; ks < 2; ++ks) {
    bf16x8 af[4], bfv[4];
    int g = ks * 4 + lh;
#pragma unroll
    for (int mi = 0; mi < 4; ++mi) {
      int r = wr * 64 + mi * 16 + l15;
      af[mi] = *(const bf16x8*)&As[0][r * 64 + (g ^ (r & 7)) * 8];
    }
#pragma unroll
    for (int ni = 0; ni < 4; ++ni) {
      int r = wc * 64 + ni * 16 + l15;
      bfv[ni] = *(const bf16x8*)&Bs[0][r * 64 + (g ^ (r & 7)) * 8];
    }
#pragma unroll
    for (int mi = 0; mi < 4; ++mi)
#pragma unroll
      for (int ni = 0; ni < 4; ++ni)
        accf[mi][ni] = __builtin_amdgcn_mfma_f32_16x16x32_bf16(af[mi], bfv[ni], accf[mi][ni], 0, 0, 0);
  }

  float gb[4];
#pragma unroll
  for (int ni = 0; ni < 4; ++ni) gb[ni] = gateB[n0 + wc * 64 + ni * 16 + l15];
#pragma unroll
  for (int mi = 0; mi < 4; ++mi)
#pragma unroll
    for (int ni = 0; ni < 4; ++ni)
#pragma unroll
      for (int r = 0; r < 4; ++r) {
        int mr = m0 + wr * 64 + mi * 16 + lh * 4 + r;
        int nc = n0 + wc * 64 + ni * 16 + l15;
        float z = accg[mi][ni][r] + gb[ni];
        float gate = 1.f / (1.f + __expf(-z));
        outp[(size_t)mr * DD + nc] = accf[mi][ni][r] * gate;
      }
}

extern "C" void kernel_launch(void* const* d_in, const int* in_sizes, int n_in,
                              void* d_out, int out_size, void* d_ws, size_t ws_size,
                              hipStream_t stream) {
  const float* tok = (const float*)d_in[0];
  const float* infl = (const float*)d_in[1];
  const float* encW = (const float*)d_in[2];
  const float* encB = (const float*)d_in[3];
  const float* trW = (const float*)d_in[4];
  const float* trB = (const float*)d_in[5];
  const float* decW = (const float*)d_in[6];
  const float* decB = (const float*)d_in[7];
  const float* gw = (const float*)d_in[8];
  const float* gateB = (const float*)d_in[9];
  float* outp = (float*)d_out;

  char* wsp = (char*)d_ws;
  u16* tokbf = (u16*)(wsp);                    // 33,554,432 B
  u16* gwt = (u16*)(wsp + 33554432);           //  2,097,152 B
  u16* inflbf = (u16*)(wsp + 35651584);        //  2,097,152 B
  float* rtot = (float*)(wsp + 37748736);      //      2,048 B
  float* gath = (float*)(wsp + 37750784);      //  2,097,152 B
  float* enc = (float*)(wsp + 39847936);       //  1,048,576 B
  float* trf = (float*)(wsp + 40896512);       //  1,048,576 B
  u16* decT = (u16*)(wsp + 41945088);          //  1,048,576 B
  u16* tokT = (u16*)(wsp + 42993664);          // 33,554,432 B
  u16* inflT = (u16*)(wsp + 76548096);         //  2,097,152 B
  float* rsum = (float*)(wsp + 78645248);      //     65,536 B
  float* scratch = (float*)(wsp + 78710784);   // 16,777,216 B shared pg/pe/pt/pd (end ~95.5 MB)

  k_prep_tok<<<dim3(16, 256), dim3(256), 0, stream>>>(tok, tokbf, tokT);
  k_prep_infl<<<dim3(256), dim3(256), 0, stream>>>(infl, inflbf, inflT, rsum);
  k_tot_fin<<<dim3(1), dim3(512), 0, stream>>>(rsum, rtot);
  k_gatewt<<<dim3(32, 32), dim3(256), 0, stream>>>(gw, gwt);
  k_gather_mfma<<<dim3(16, 8, 4), dim3(256), 0, stream>>>(inflT, tokT, scratch);
  red_gath<<<dim3(512), dim3(256), 0, stream>>>(scratch, rtot, gath);
  k_enc_part<<<dim3(16, 64), dim3(256), 0, stream>>>(gath, encW, scratch);
  red_enc<<<dim3(256), dim3(256), 0, stream>>>(scratch, encB, enc);
  k_trans_part<<<dim3(16, 64), dim3(256), 0, stream>>>(enc, trW, scratch);
  red_trans<<<dim3(256), dim3(256), 0, stream>>>(scratch, trB, trf);
  k_dec_part<<<dim3(8, 64), dim3(256), 0, stream>>>(trf, decW, scratch);
  red_dec<<<dim3(32, 8), dim3(256), 0, stream>>>(scratch, decB, decT);
  k_out<<<dim3(128, 4), dim3(512), 0, stream>>>(tokbf, gwt, inflbf, decT, gateB, outp);
}

// Round 5
// 180.526 us; speedup vs baseline: 2.8939x; 1.0325x over previous
//
#include <hip/hip_runtime.h>

#define BB 8
#define SS 2048
#define DD 1024
#define BDD 512
#define NSP 64

typedef __attribute__((ext_vector_type(8))) short bf16x8;
typedef __attribute__((ext_vector_type(4))) float f32x4;
typedef unsigned short u16;
typedef unsigned int u32;

__device__ __forceinline__ u16 f2bf(float f) {
  u32 u = __builtin_bit_cast(u32, f);
  u = u + 0x7fffu + ((u >> 16) & 1u);
  return (u16)(u >> 16);
}

__device__ __forceinline__ void gl_lds16(const void* g, void* l) {
  __builtin_amdgcn_global_load_lds((const __attribute__((address_space(1))) void*)g,
                                   (__attribute__((address_space(3))) void*)l,
                                   16, 0, 0);
}

// ---------- fused: tok f32 -> tokbf (bf16 row-major) + tokT (bf16 [b][d][s]) ----------
__global__ void k_prep_tok(const float* __restrict__ tok, u16* __restrict__ tokbf,
                           u16* __restrict__ tokT) {
  __shared__ u16 tile[64][80];
  int C0 = blockIdx.x * 64;
  int R0 = blockIdx.y * 64;
  int b = R0 >> 11, s0 = R0 & 2047;
  int t = threadIdx.x;
  int lr = t >> 3, lc = (t & 7) * 8;
#pragma unroll
  for (int i = 0; i < 2; ++i) {
    int r = lr + i * 32;
    const float* src = tok + (size_t)(R0 + r) * DD + C0 + lc;
    float4 a = *(const float4*)src;
    float4 bq = *(const float4*)(src + 4);
    uint4 v;
    v.x = f2bf(a.x) | ((u32)f2bf(a.y) << 16);
    v.y = f2bf(a.z) | ((u32)f2bf(a.w) << 16);
    v.z = f2bf(bq.x) | ((u32)f2bf(bq.y) << 16);
    v.w = f2bf(bq.z) | ((u32)f2bf(bq.w) << 16);
    *(uint4*)(tokbf + (size_t)(R0 + r) * DD + C0 + lc) = v;
    *(uint4*)&tile[r][lc] = v;
  }
  __syncthreads();
  int sseg = (t & 7) * 8;
#pragma unroll
  for (int i = 0; i < 2; ++i) {
    int dcol = (t >> 3) + i * 32;
    u16 a0 = tile[sseg + 0][dcol], a1 = tile[sseg + 1][dcol];
    u16 a2 = tile[sseg + 2][dcol], a3 = tile[sseg + 3][dcol];
    u16 a4 = tile[sseg + 4][dcol], a5 = tile[sseg + 5][dcol];
    u16 a6 = tile[sseg + 6][dcol], a7 = tile[sseg + 7][dcol];
    uint4 v;
    v.x = a0 | ((u32)a1 << 16);
    v.y = a2 | ((u32)a3 << 16);
    v.z = a4 | ((u32)a5 << 16);
    v.w = a6 | ((u32)a7 << 16);
    *(uint4*)(tokT + (size_t)b * DD * SS + (size_t)(C0 + dcol) * SS + s0 + sseg) = v;
  }
}

// ---------- fused: infl f32 -> inflbf + inflT + per-tile column sums ----------
__global__ void k_prep_infl(const float* __restrict__ infl, u16* __restrict__ inflbf,
                            u16* __restrict__ inflT, float* __restrict__ rsum) {
  __shared__ u16 tile[64][80];
  __shared__ float ps[32][64];
  int R0 = blockIdx.x * 64;
  int b = R0 >> 11, s0 = R0 & 2047;
  int st = s0 >> 6;
  int t = threadIdx.x;
  int lr = t >> 3, lc = (t & 7) * 8;
  float col[8];
#pragma unroll
  for (int j = 0; j < 8; ++j) col[j] = 0.f;
#pragma unroll
  for (int i = 0; i < 2; ++i) {
    int r = lr + i * 32;
    const float* src = infl + (size_t)(R0 + r) * NSP + lc;
    float4 a = *(const float4*)src;
    float4 bq = *(const float4*)(src + 4);
    col[0] += a.x; col[1] += a.y; col[2] += a.z; col[3] += a.w;
    col[4] += bq.x; col[5] += bq.y; col[6] += bq.z; col[7] += bq.w;
    uint4 v;
    v.x = f2bf(a.x) | ((u32)f2bf(a.y) << 16);
    v.y = f2bf(a.z) | ((u32)f2bf(a.w) << 16);
    v.z = f2bf(bq.x) | ((u32)f2bf(bq.y) << 16);
    v.w = f2bf(bq.z) | ((u32)f2bf(bq.w) << 16);
    *(uint4*)(inflbf + (size_t)(R0 + r) * NSP + lc) = v;
    *(uint4*)&tile[r][lc] = v;
  }
#pragma unroll
  for (int j = 0; j < 8; ++j) ps[lr][lc + j] = col[j];
  __syncthreads();
  if (t < 64) {
    float s = 0.f;
#pragma unroll
    for (int rr = 0; rr < 32; ++rr) s += ps[rr][t];
    rsum[((size_t)b * 32 + st) * 64 + t] = s;
  }
  int sseg = (t & 7) * 8;
#pragma unroll
  for (int i = 0; i < 2; ++i) {
    int dcol = (t >> 3) + i * 32;
    u16 a0 = tile[sseg + 0][dcol], a1 = tile[sseg + 1][dcol];
    u16 a2 = tile[sseg + 2][dcol], a3 = tile[sseg + 3][dcol];
    u16 a4 = tile[sseg + 4][dcol], a5 = tile[sseg + 5][dcol];
    u16 a6 = tile[sseg + 6][dcol], a7 = tile[sseg + 7][dcol];
    uint4 v;
    v.x = a0 | ((u32)a1 << 16);
    v.y = a2 | ((u32)a3 << 16);
    v.z = a4 | ((u32)a5 << 16);
    v.w = a6 | ((u32)a7 << 16);
    *(uint4*)(inflT + ((size_t)b * NSP + dcol) * SS + s0 + sseg) = v;
  }
}

// ---------- finalize totals -> reciprocal ----------
__global__ void k_tot_fin(const float* __restrict__ rsum, float* __restrict__ rtot) {
  int t = threadIdx.x;  // 512 = 8b x 64k
  float s = 0.f;
#pragma unroll
  for (int st = 0; st < 32; ++st)
    s += rsum[((size_t)(t >> 6) * 32 + st) * 64 + (t & 63)];
  rtot[t] = 1.f / fmaxf(s, 1e-8f);
}

// ---------- gate_W [k][n] f32 -> gwt [n][k] bf16 ----------
__global__ void k_gatewt(const float* __restrict__ gw, u16* __restrict__ gwt) {
  __shared__ float tile[32][33];
  int n0 = blockIdx.x * 32, k0 = blockIdx.y * 32;
  int tx = threadIdx.x & 31, ty = threadIdx.x >> 5;
#pragma unroll
  for (int r = 0; r < 4; ++r) {
    int kr = ty + r * 8;
    tile[kr][tx] = gw[(k0 + kr) * DD + n0 + tx];
  }
  __syncthreads();
#pragma unroll
  for (int r = 0; r < 4; ++r) {
    int nc = ty + r * 8;
    gwt[(n0 + nc) * DD + k0 + tx] = f2bf(tile[tx][nc]);
  }
}

// ---------- MFMA gather partials: pg[sq][b*64+k][d] ----------
__global__ __launch_bounds__(256) void k_gather_mfma(const u16* __restrict__ inflT,
                                                     const u16* __restrict__ tokT,
                                                     float* __restrict__ pg) {
  __shared__ u16 As[64 * 64];
  __shared__ u16 Bs[64 * 64];
  int t = threadIdx.x;
  int l = t & 63, w = t >> 6;
  int wr = w >> 1, wc = w & 1;
  int n0 = blockIdx.x * 64;
  int b = blockIdx.y;
  int sq = blockIdx.z;
  int l15 = l & 15, lh = l >> 4;
  int srow = t >> 3, scol = (t & 7) * 8;

  const u16* ap = inflT + (size_t)b * NSP * SS;
  const u16* bp = tokT + (size_t)b * DD * SS;

  f32x4 acc[2][2];
#pragma unroll
  for (int i = 0; i < 2; ++i)
#pragma unroll
    for (int j = 0; j < 2; ++j) acc[i][j] = (f32x4){0.f, 0.f, 0.f, 0.f};

  for (int kt = 0; kt < 8; ++kt) {
    int k0 = sq * 512 + kt * 64;
#pragma unroll
    for (int i = 0; i < 2; ++i) {
      int row = srow + i * 32;
      gl_lds16(ap + row * SS + k0 + scol, &As[row * 64 + scol]);
      gl_lds16(bp + (n0 + row) * SS + k0 + scol, &Bs[row * 64 + scol]);
    }
    __syncthreads();
#pragma unroll
    for (int ks = 0; ks < 2; ++ks) {
      bf16x8 af[2], bfv[2];
#pragma unroll
      for (int mi = 0; mi < 2; ++mi)
        af[mi] = *(const bf16x8*)&As[(wr * 32 + mi * 16 + l15) * 64 + ks * 32 + lh * 8];
#pragma unroll
      for (int ni = 0; ni < 2; ++ni)
        bfv[ni] = *(const bf16x8*)&Bs[(wc * 32 + ni * 16 + l15) * 64 + ks * 32 + lh * 8];
#pragma unroll
      for (int mi = 0; mi < 2; ++mi)
#pragma unroll
        for (int ni = 0; ni < 2; ++ni)
          acc[mi][ni] = __builtin_amdgcn_mfma_f32_16x16x32_bf16(af[mi], bfv[ni], acc[mi][ni], 0, 0, 0);
    }
    __syncthreads();
  }

#pragma unroll
  for (int mi = 0; mi < 2; ++mi)
#pragma unroll
    for (int ni = 0; ni < 2; ++ni)
#pragma unroll
      for (int r = 0; r < 4; ++r) {
        int krow = wr * 32 + mi * 16 + lh * 4 + r;
        int dcol = n0 + wc * 32 + ni * 16 + l15;
        pg[((size_t)sq * 512 + b * NSP + krow) * DD + dcol] = acc[mi][ni][r];
      }
}

// ---------- enc partials (fused gather-reduce + rtot): pe[dq][m][n] ----------
// grid (16 dq, 64 mt), block 256
__global__ void k_enc_part(const float* __restrict__ pg, const float* __restrict__ rtot,
                           const float* __restrict__ encW, float* __restrict__ pe) {
  __shared__ float gl[8][64];
  int dq = blockIdx.x, mt = blockIdx.y;
  int m0 = mt * 8, d0 = dq * 64;
  int t = threadIdx.x;
  {
    int r = t >> 5, c = t & 31;
    float s1 = 0.f, s2 = 0.f;
#pragma unroll
    for (int q = 0; q < 4; ++q) {
      const float* qp = pg + ((size_t)q * 512 + m0 + r) * DD + d0;
      s1 += qp[c]; s2 += qp[c + 32];
    }
    float rt = rtot[m0 + r];
    gl[r][c] = s1 * rt;
    gl[r][c + 32] = s2 * rt;
  }
  __syncthreads();
  int n4 = (t & 127) * 4, mh = (t >> 7) * 4;
  float4 acc[4];
#pragma unroll
  for (int m = 0; m < 4; ++m) acc[m] = (float4){0.f, 0.f, 0.f, 0.f};
  for (int i = 0; i < 64; ++i) {
    float4 wv = *(const float4*)(encW + (d0 + i) * BDD + n4);
#pragma unroll
    for (int m = 0; m < 4; ++m) {
      float g = gl[mh + m][i];
      acc[m].x += g * wv.x; acc[m].y += g * wv.y;
      acc[m].z += g * wv.z; acc[m].w += g * wv.w;
    }
  }
#pragma unroll
  for (int m = 0; m < 4; ++m)
    *(float4*)(pe + ((size_t)dq * 512 + m0 + mh + m) * BDD + n4) = acc[m];
}

// ---------- trans partials (fused enc-reduce + bias + relu): pt[dq][b*64+ks][e] ----------
// grid (16 dq, 64 ks), block 256
__global__ void k_trans_part(const float* __restrict__ pe, const float* __restrict__ encB,
                             const float* __restrict__ trW, float* __restrict__ pt) {
  __shared__ float el[8][32];
  int dq = blockIdx.x, ks = blockIdx.y;
  int d0 = dq * 32;
  int t = threadIdx.x;
  {
    int r = t >> 5, c = t & 31;
    int m = r * NSP + ks;
    float s = 0.f;
#pragma unroll
    for (int p = 0; p < 16; ++p)
      s += pe[((size_t)p * 512 + m) * BDD + d0 + c];
    el[r][c] = fmaxf(s + encB[d0 + c], 0.f);
  }
  __syncthreads();
  int n4 = (t & 127) * 4, mh = (t >> 7) * 4;
  float4 acc[4];
#pragma unroll
  for (int m = 0; m < 4; ++m) acc[m] = (float4){0.f, 0.f, 0.f, 0.f};
  for (int i = 0; i < 32; ++i) {
    float4 wv = *(const float4*)(trW + ((size_t)ks * BDD + d0 + i) * BDD + n4);
#pragma unroll
    for (int m = 0; m < 4; ++m) {
      float g = el[mh + m][i];
      acc[m].x += g * wv.x; acc[m].y += g * wv.y;
      acc[m].z += g * wv.z; acc[m].w += g * wv.w;
    }
  }
#pragma unroll
  for (int m = 0; m < 4; ++m)
    *(float4*)(pt + ((size_t)dq * 512 + (mh + m) * NSP + ks) * BDD + n4) = acc[m];
}

// ---------- dec partials (fused trans-reduce + bias): pd[dq][m][n] ----------
// grid (8 dq, 64 mt), block 256
__global__ void k_dec_part(const float* __restrict__ pt, const float* __restrict__ trB,
                           const float* __restrict__ decW, float* __restrict__ pd) {
  __shared__ float tl[8][64];
  int dq = blockIdx.x, mt = blockIdx.y;
  int m0 = mt * 8, d0 = dq * 64;
  int t = threadIdx.x;
  {
    int r = t >> 5, c = t & 31;
    int m = m0 + r;
    float s1 = 0.f, s2 = 0.f;
#pragma unroll
    for (int p = 0; p < 16; ++p) {
      const float* qp = pt + ((size_t)p * 512 + m) * BDD + d0;
      s1 += qp[c]; s2 += qp[c + 32];
    }
    tl[r][c] = s1 + trB[(m & 63) * BDD + d0 + c];
    tl[r][c + 32] = s2 + trB[(m & 63) * BDD + d0 + c + 32];
  }
  __syncthreads();
  int n4 = t * 4;
  float4 acc[8];
#pragma unroll
  for (int m = 0; m < 8; ++m) acc[m] = (float4){0.f, 0.f, 0.f, 0.f};
  for (int i = 0; i < 64; ++i) {
    float4 wv = *(const float4*)(decW + (d0 + i) * DD + n4);
#pragma unroll
    for (int m = 0; m < 8; ++m) {
      float g = tl[m][i];
      acc[m].x += g * wv.x; acc[m].y += g * wv.y;
      acc[m].z += g * wv.z; acc[m].w += g * wv.w;
    }
  }
#pragma unroll
  for (int m = 0; m < 8; ++m)
    *(float4*)(pd + ((size_t)dq * 512 + m0 + m) * DD + n4) = acc[m];
}

// ---------- reduce dec partials + bias -> decT[b][n][ks] bf16 ----------
__global__ void red_dec(const float* __restrict__ pd, const float* __restrict__ decB,
                        u16* __restrict__ decT) {
  __shared__ u16 st[64][34];
  int nt = blockIdx.x, b = blockIdx.y;
  int n0 = nt * 32;
  int t = threadIdx.x;
  int nn = t & 31, kg = t >> 5;
  float db = decB[n0 + nn];
#pragma unroll
  for (int ki = 0; ki < 8; ++ki) {
    int ks = kg * 8 + ki;
    float s = db;
#pragma unroll
    for (int p = 0; p < 8; ++p)
      s += pd[((size_t)p * 512 + b * NSP + ks) * DD + n0 + nn];
    st[ks][nn] = f2bf(s);
  }
  __syncthreads();
  int nr = t >> 3, kseg = (t & 7) * 8;
  uint4 v;
  v.x = st[kseg + 0][nr] | ((u32)st[kseg + 1][nr] << 16);
  v.y = st[kseg + 2][nr] | ((u32)st[kseg + 3][nr] << 16);
  v.z = st[kseg + 4][nr] | ((u32)st[kseg + 5][nr] << 16);
  v.w = st[kseg + 6][nr] | ((u32)st[kseg + 7][nr] << 16);
  *(uint4*)(decT + ((size_t)b * DD + n0 + nr) * NSP + kseg) = v;
}

// ---------- fused gate GEMM + scatter + sigmoid*flow; depth-2 prefetch, counted vmcnt ----------
// BM=128, BN=256, BK=64; 512 threads (8 waves 2x4); 3-slot LDS pipeline (144KB).
__global__ __launch_bounds__(512) void k_out(const u16* __restrict__ tokbf,
                                             const u16* __restrict__ gwt,
                                             const u16* __restrict__ inflbf,
                                             const u16* __restrict__ decT,
                                             const float* __restrict__ gateB,
                                             float* __restrict__ outp) {
  __shared__ u16 As[3][128 * 64];
  __shared__ u16 Bs[3][256 * 64];
  int t = threadIdx.x;
  int l = t & 63, w = t >> 6;
  int wr = w >> 2, wc = w & 3;  // 2 x 4 waves, 64x64 per wave
  int m0 = blockIdx.x * 128, n0 = blockIdx.y * 256;
  int l15 = l & 15, lh = l >> 4;

  auto stage = [&](int sl, int kt) {
    int k0 = kt * 64;
#pragma unroll
    for (int p = 0; p < 2; ++p) {
      int e = p * 512 + t;
      int row = e >> 3, csrc = ((e & 7) ^ (row & 7)) * 8;
      gl_lds16(tokbf + (size_t)(m0 + row) * DD + k0 + csrc, &As[sl][e * 8]);
    }
#pragma unroll
    for (int p = 0; p < 4; ++p) {
      int e = p * 512 + t;
      int row = e >> 3, csrc = ((e & 7) ^ (row & 7)) * 8;
      gl_lds16(gwt + (size_t)(n0 + row) * DD + k0 + csrc, &Bs[sl][e * 8]);
    }
  };

  auto compute = [&](int sl, f32x4 (&acc)[4][4]) {
#pragma unroll
    for (int ks = 0; ks < 2; ++ks) {
      bf16x8 af[4], bfv[4];
      int g = ks * 4 + lh;
#pragma unroll
      for (int mi = 0; mi < 4; ++mi) {
        int r = wr * 64 + mi * 16 + l15;
        af[mi] = *(const bf16x8*)&As[sl][r * 64 + (g ^ (r & 7)) * 8];
      }
#pragma unroll
      for (int ni = 0; ni < 4; ++ni) {
        int r = wc * 64 + ni * 16 + l15;
        bfv[ni] = *(const bf16x8*)&Bs[sl][r * 64 + (g ^ (r & 7)) * 8];
      }
      __builtin_amdgcn_s_setprio(1);
#pragma unroll
      for (int mi = 0; mi < 4; ++mi)
#pragma unroll
        for (int ni = 0; ni < 4; ++ni)
          acc[mi][ni] = __builtin_amdgcn_mfma_f32_16x16x32_bf16(af[mi], bfv[ni], acc[mi][ni], 0, 0, 0);
      __builtin_amdgcn_s_setprio(0);
    }
  };

  f32x4 accg[4][4];
#pragma unroll
  for (int i = 0; i < 4; ++i)
#pragma unroll
    for (int j = 0; j < 4; ++j) accg[i][j] = (f32x4){0.f, 0.f, 0.f, 0.f};

  // prologue: tiles 0 and 1 in flight
  stage(0, 0);
  stage(1, 1);

  for (int kt = 0; kt < 14; ++kt) {
    stage((kt + 2) % 3, kt + 2);                     // keep 2 tiles in flight
    asm volatile("s_waitcnt vmcnt(12)" ::: "memory"); // tile kt done; 12 newer stay in flight
    __builtin_amdgcn_s_barrier();
    compute(kt % 3, accg);
    __builtin_amdgcn_s_barrier();                     // protect slot reuse
  }
  asm volatile("s_waitcnt vmcnt(6)" ::: "memory");    // tile 14 done
  __builtin_amdgcn_s_barrier();
  compute(2, accg);
  __builtin_amdgcn_s_barrier();
  asm volatile("s_waitcnt vmcnt(0)" ::: "memory");    // tile 15 done
  __builtin_amdgcn_s_barrier();
  compute(0, accg);
  __builtin_amdgcn_s_barrier();

  // scatter pass: K = 64 splats, stage into slot 0
  int b = m0 >> 11;
  int s0m = m0 & 2047;
#pragma unroll
  for (int p = 0; p < 2; ++p) {
    int e = p * 512 + t;
    int row = e >> 3, csrc = ((e & 7) ^ (row & 7)) * 8;
    gl_lds16(inflbf + ((size_t)b * SS + s0m + row) * NSP + csrc, &As[0][e * 8]);
  }
#pragma unroll
  for (int p = 0; p < 4; ++p) {
    int e = p * 512 + t;
    int row = e >> 3, csrc = ((e & 7) ^ (row & 7)) * 8;
    gl_lds16(decT + ((size_t)b * DD + n0 + row) * NSP + csrc, &Bs[0][e * 8]);
  }
  asm volatile("s_waitcnt vmcnt(0)" ::: "memory");
  __builtin_amdgcn_s_barrier();

  f32x4 accf[4][4];
#pragma unroll
  for (int i = 0; i < 4; ++i)
#pragma unroll
    for (int j = 0; j < 4; ++j) accf[i][j] = (f32x4){0.f, 0.f, 0.f, 0.f};
  compute(0, accf);

  float gb[4];
#pragma unroll
  for (int ni = 0; ni < 4; ++ni) gb[ni] = gateB[n0 + wc * 64 + ni * 16 + l15];
#pragma unroll
  for (int mi = 0; mi < 4; ++mi)
#pragma unroll
    for (int ni = 0; ni < 4; ++ni)
#pragma unroll
      for (int r = 0; r < 4; ++r) {
        int mr = m0 + wr * 64 + mi * 16 + lh * 4 + r;
        int nc = n0 + wc * 64 + ni * 16 + l15;
        float z = accg[mi][ni][r] + gb[ni];
        float gate = 1.f / (1.f + __expf(-z));
        outp[(size_t)mr * DD + nc] = accf[mi][ni][r] * gate;
      }
}

extern "C" void kernel_launch(void* const* d_in, const int* in_sizes, int n_in,
                              void* d_out, int out_size, void* d_ws, size_t ws_size,
                              hipStream_t stream) {
  const float* tok = (const float*)d_in[0];
  const float* infl = (const float*)d_in[1];
  const float* encW = (const float*)d_in[2];
  const float* encB = (const float*)d_in[3];
  const float* trW = (const float*)d_in[4];
  const float* trB = (const float*)d_in[5];
  const float* decW = (const float*)d_in[6];
  const float* decB = (const float*)d_in[7];
  const float* gw = (const float*)d_in[8];
  const float* gateB = (const float*)d_in[9];
  float* outp = (float*)d_out;

  char* wsp = (char*)d_ws;
  u16* tokbf = (u16*)(wsp);                    // 33,554,432 B
  u16* gwt = (u16*)(wsp + 33554432);           //  2,097,152 B
  u16* inflbf = (u16*)(wsp + 35651584);        //  2,097,152 B
  float* rtot = (float*)(wsp + 37748736);      //      2,048 B
  u16* decT = (u16*)(wsp + 41945088);          //  1,048,576 B
  u16* tokT = (u16*)(wsp + 42993664);          // 33,554,432 B (dead after gather)
  float* pe = (float*)(wsp + 42993664);        //   overlays tokT[0:16MB]
  float* pt = (float*)(wsp + 42993664 + 16777216);  // overlays tokT[16:32MB]
  u16* inflT = (u16*)(wsp + 76548096);         //  2,097,152 B
  float* rsum = (float*)(wsp + 78645248);      //     65,536 B
  float* scratch = (float*)(wsp + 78710784);   // 16,777,216 B: pg then pd (end ~95.5 MB)

  k_prep_tok<<<dim3(16, 256), dim3(256), 0, stream>>>(tok, tokbf, tokT);
  k_prep_infl<<<dim3(256), dim3(256), 0, stream>>>(infl, inflbf, inflT, rsum);
  k_tot_fin<<<dim3(1), dim3(512), 0, stream>>>(rsum, rtot);
  k_gatewt<<<dim3(32, 32), dim3(256), 0, stream>>>(gw, gwt);
  k_gather_mfma<<<dim3(16, 8, 4), dim3(256), 0, stream>>>(inflT, tokT, scratch);
  k_enc_part<<<dim3(16, 64), dim3(256), 0, stream>>>(scratch, rtot, encW, pe);
  k_trans_part<<<dim3(16, 64), dim3(256), 0, stream>>>(pe, encB, trW, pt);
  k_dec_part<<<dim3(8, 64), dim3(256), 0, stream>>>(pt, trB, decW, scratch);
  red_dec<<<dim3(32, 8), dim3(256), 0, stream>>>(scratch, decB, decT);
  k_out<<<dim3(128, 4), dim3(512), 0, stream>>>(tokbf, gwt, inflbf, decT, gateB, outp);
}

// Round 6
// 173.397 us; speedup vs baseline: 3.0128x; 1.0411x over previous
//
#include <hip/hip_runtime.h>

#define BB 8
#define SS 2048
#define DD 1024
#define BDD 512
#define NSP 64

typedef __attribute__((ext_vector_type(8))) short bf16x8;
typedef __attribute__((ext_vector_type(4))) float f32x4;
typedef unsigned short u16;
typedef unsigned int u32;

__device__ __forceinline__ u16 f2bf(float f) {
  u32 u = __builtin_bit_cast(u32, f);
  u = u + 0x7fffu + ((u >> 16) & 1u);
  return (u16)(u >> 16);
}

__device__ __forceinline__ void gl_lds16(const void* g, void* l) {
  __builtin_amdgcn_global_load_lds((const __attribute__((address_space(1))) void*)g,
                                   (__attribute__((address_space(3))) void*)l,
                                   16, 0, 0);
}

// ---------- fused: tok f32 -> tokbf (bf16 row-major) + tokT (bf16 [b][d][s]) ----------
__global__ void k_prep_tok(const float* __restrict__ tok, u16* __restrict__ tokbf,
                           u16* __restrict__ tokT) {
  __shared__ u16 tile[64][80];
  int C0 = blockIdx.x * 64;
  int R0 = blockIdx.y * 64;
  int b = R0 >> 11, s0 = R0 & 2047;
  int t = threadIdx.x;
  int lr = t >> 3, lc = (t & 7) * 8;
#pragma unroll
  for (int i = 0; i < 2; ++i) {
    int r = lr + i * 32;
    const float* src = tok + (size_t)(R0 + r) * DD + C0 + lc;
    float4 a = *(const float4*)src;
    float4 bq = *(const float4*)(src + 4);
    uint4 v;
    v.x = f2bf(a.x) | ((u32)f2bf(a.y) << 16);
    v.y = f2bf(a.z) | ((u32)f2bf(a.w) << 16);
    v.z = f2bf(bq.x) | ((u32)f2bf(bq.y) << 16);
    v.w = f2bf(bq.z) | ((u32)f2bf(bq.w) << 16);
    *(uint4*)(tokbf + (size_t)(R0 + r) * DD + C0 + lc) = v;
    *(uint4*)&tile[r][lc] = v;
  }
  __syncthreads();
  int sseg = (t & 7) * 8;
#pragma unroll
  for (int i = 0; i < 2; ++i) {
    int dcol = (t >> 3) + i * 32;
    u16 a0 = tile[sseg + 0][dcol], a1 = tile[sseg + 1][dcol];
    u16 a2 = tile[sseg + 2][dcol], a3 = tile[sseg + 3][dcol];
    u16 a4 = tile[sseg + 4][dcol], a5 = tile[sseg + 5][dcol];
    u16 a6 = tile[sseg + 6][dcol], a7 = tile[sseg + 7][dcol];
    uint4 v;
    v.x = a0 | ((u32)a1 << 16);
    v.y = a2 | ((u32)a3 << 16);
    v.z = a4 | ((u32)a5 << 16);
    v.w = a6 | ((u32)a7 << 16);
    *(uint4*)(tokT + (size_t)b * DD * SS + (size_t)(C0 + dcol) * SS + s0 + sseg) = v;
  }
}

// ---------- fused: infl f32 -> inflbf + inflT + per-tile column sums ----------
__global__ void k_prep_infl(const float* __restrict__ infl, u16* __restrict__ inflbf,
                            u16* __restrict__ inflT, float* __restrict__ rsum) {
  __shared__ u16 tile[64][80];
  __shared__ float ps[32][64];
  int R0 = blockIdx.x * 64;
  int b = R0 >> 11, s0 = R0 & 2047;
  int st = s0 >> 6;
  int t = threadIdx.x;
  int lr = t >> 3, lc = (t & 7) * 8;
  float col[8];
#pragma unroll
  for (int j = 0; j < 8; ++j) col[j] = 0.f;
#pragma unroll
  for (int i = 0; i < 2; ++i) {
    int r = lr + i * 32;
    const float* src = infl + (size_t)(R0 + r) * NSP + lc;
    float4 a = *(const float4*)src;
    float4 bq = *(const float4*)(src + 4);
    col[0] += a.x; col[1] += a.y; col[2] += a.z; col[3] += a.w;
    col[4] += bq.x; col[5] += bq.y; col[6] += bq.z; col[7] += bq.w;
    uint4 v;
    v.x = f2bf(a.x) | ((u32)f2bf(a.y) << 16);
    v.y = f2bf(a.z) | ((u32)f2bf(a.w) << 16);
    v.z = f2bf(bq.x) | ((u32)f2bf(bq.y) << 16);
    v.w = f2bf(bq.z) | ((u32)f2bf(bq.w) << 16);
    *(uint4*)(inflbf + (size_t)(R0 + r) * NSP + lc) = v;
    *(uint4*)&tile[r][lc] = v;
  }
#pragma unroll
  for (int j = 0; j < 8; ++j) ps[lr][lc + j] = col[j];
  __syncthreads();
  if (t < 64) {
    float s = 0.f;
#pragma unroll
    for (int rr = 0; rr < 32; ++rr) s += ps[rr][t];
    rsum[((size_t)b * 32 + st) * 64 + t] = s;
  }
  int sseg = (t & 7) * 8;
#pragma unroll
  for (int i = 0; i < 2; ++i) {
    int dcol = (t >> 3) + i * 32;
    u16 a0 = tile[sseg + 0][dcol], a1 = tile[sseg + 1][dcol];
    u16 a2 = tile[sseg + 2][dcol], a3 = tile[sseg + 3][dcol];
    u16 a4 = tile[sseg + 4][dcol], a5 = tile[sseg + 5][dcol];
    u16 a6 = tile[sseg + 6][dcol], a7 = tile[sseg + 7][dcol];
    uint4 v;
    v.x = a0 | ((u32)a1 << 16);
    v.y = a2 | ((u32)a3 << 16);
    v.z = a4 | ((u32)a5 << 16);
    v.w = a6 | ((u32)a7 << 16);
    *(uint4*)(inflT + ((size_t)b * NSP + dcol) * SS + s0 + sseg) = v;
  }
}

// ---------- finalize totals -> reciprocal ----------
__global__ void k_tot_fin(const float* __restrict__ rsum, float* __restrict__ rtot) {
  int t = threadIdx.x;  // 512 = 8b x 64k
  float s = 0.f;
#pragma unroll
  for (int st = 0; st < 32; ++st)
    s += rsum[((size_t)(t >> 6) * 32 + st) * 64 + (t & 63)];
  rtot[t] = 1.f / fmaxf(s, 1e-8f);
}

// ---------- gate_W [k][n] f32 -> gwt [n][k] bf16 ----------
__global__ void k_gatewt(const float* __restrict__ gw, u16* __restrict__ gwt) {
  __shared__ float tile[32][33];
  int n0 = blockIdx.x * 32, k0 = blockIdx.y * 32;
  int tx = threadIdx.x & 31, ty = threadIdx.x >> 5;
#pragma unroll
  for (int r = 0; r < 4; ++r) {
    int kr = ty + r * 8;
    tile[kr][tx] = gw[(k0 + kr) * DD + n0 + tx];
  }
  __syncthreads();
#pragma unroll
  for (int r = 0; r < 4; ++r) {
    int nc = ty + r * 8;
    gwt[(n0 + nc) * DD + k0 + tx] = f2bf(tile[tx][nc]);
  }
}

// ---------- MFMA gather partials: pg[sq][b*64+k][d] ----------
__global__ __launch_bounds__(256) void k_gather_mfma(const u16* __restrict__ inflT,
                                                     const u16* __restrict__ tokT,
                                                     float* __restrict__ pg) {
  __shared__ u16 As[64 * 64];
  __shared__ u16 Bs[64 * 64];
  int t = threadIdx.x;
  int l = t & 63, w = t >> 6;
  int wr = w >> 1, wc = w & 1;
  int n0 = blockIdx.x * 64;
  int b = blockIdx.y;
  int sq = blockIdx.z;
  int l15 = l & 15, lh = l >> 4;
  int srow = t >> 3, scol = (t & 7) * 8;

  const u16* ap = inflT + (size_t)b * NSP * SS;
  const u16* bp = tokT + (size_t)b * DD * SS;

  f32x4 acc[2][2];
#pragma unroll
  for (int i = 0; i < 2; ++i)
#pragma unroll
    for (int j = 0; j < 2; ++j) acc[i][j] = (f32x4){0.f, 0.f, 0.f, 0.f};

  for (int kt = 0; kt < 8; ++kt) {
    int k0 = sq * 512 + kt * 64;
#pragma unroll
    for (int i = 0; i < 2; ++i) {
      int row = srow + i * 32;
      gl_lds16(ap + row * SS + k0 + scol, &As[row * 64 + scol]);
      gl_lds16(bp + (n0 + row) * SS + k0 + scol, &Bs[row * 64 + scol]);
    }
    __syncthreads();
#pragma unroll
    for (int ks = 0; ks < 2; ++ks) {
      bf16x8 af[2], bfv[2];
#pragma unroll
      for (int mi = 0; mi < 2; ++mi)
        af[mi] = *(const bf16x8*)&As[(wr * 32 + mi * 16 + l15) * 64 + ks * 32 + lh * 8];
#pragma unroll
      for (int ni = 0; ni < 2; ++ni)
        bfv[ni] = *(const bf16x8*)&Bs[(wc * 32 + ni * 16 + l15) * 64 + ks * 32 + lh * 8];
#pragma unroll
      for (int mi = 0; mi < 2; ++mi)
#pragma unroll
        for (int ni = 0; ni < 2; ++ni)
          acc[mi][ni] = __builtin_amdgcn_mfma_f32_16x16x32_bf16(af[mi], bfv[ni], acc[mi][ni], 0, 0, 0);
    }
    __syncthreads();
  }

#pragma unroll
  for (int mi = 0; mi < 2; ++mi)
#pragma unroll
    for (int ni = 0; ni < 2; ++ni)
#pragma unroll
      for (int r = 0; r < 4; ++r) {
        int krow = wr * 32 + mi * 16 + lh * 4 + r;
        int dcol = n0 + wc * 32 + ni * 16 + l15;
        pg[((size_t)sq * 512 + b * NSP + krow) * DD + dcol] = acc[mi][ni][r];
      }
}

// ---------- enc partials (fused gather-reduce + rtot): pe[dq][m][n] ----------
__global__ void k_enc_part(const float* __restrict__ pg, const float* __restrict__ rtot,
                           const float* __restrict__ encW, float* __restrict__ pe) {
  __shared__ float gl[8][64];
  int dq = blockIdx.x, mt = blockIdx.y;
  int m0 = mt * 8, d0 = dq * 64;
  int t = threadIdx.x;
  {
    int r = t >> 5, c = t & 31;
    float s1 = 0.f, s2 = 0.f;
#pragma unroll
    for (int q = 0; q < 4; ++q) {
      const float* qp = pg + ((size_t)q * 512 + m0 + r) * DD + d0;
      s1 += qp[c]; s2 += qp[c + 32];
    }
    float rt = rtot[m0 + r];
    gl[r][c] = s1 * rt;
    gl[r][c + 32] = s2 * rt;
  }
  __syncthreads();
  int n4 = (t & 127) * 4, mh = (t >> 7) * 4;
  float4 acc[4];
#pragma unroll
  for (int m = 0; m < 4; ++m) acc[m] = (float4){0.f, 0.f, 0.f, 0.f};
  for (int i = 0; i < 64; ++i) {
    float4 wv = *(const float4*)(encW + (d0 + i) * BDD + n4);
#pragma unroll
    for (int m = 0; m < 4; ++m) {
      float g = gl[mh + m][i];
      acc[m].x += g * wv.x; acc[m].y += g * wv.y;
      acc[m].z += g * wv.z; acc[m].w += g * wv.w;
    }
  }
#pragma unroll
  for (int m = 0; m < 4; ++m)
    *(float4*)(pe + ((size_t)dq * 512 + m0 + mh + m) * BDD + n4) = acc[m];
}

// ---------- trans partials (fused enc-reduce + bias + relu): pt[dq][b*64+ks][e] ----------
__global__ void k_trans_part(const float* __restrict__ pe, const float* __restrict__ encB,
                             const float* __restrict__ trW, float* __restrict__ pt) {
  __shared__ float el[8][32];
  int dq = blockIdx.x, ks = blockIdx.y;
  int d0 = dq * 32;
  int t = threadIdx.x;
  {
    int r = t >> 5, c = t & 31;
    int m = r * NSP + ks;
    float s = 0.f;
#pragma unroll
    for (int p = 0; p < 16; ++p)
      s += pe[((size_t)p * 512 + m) * BDD + d0 + c];
    el[r][c] = fmaxf(s + encB[d0 + c], 0.f);
  }
  __syncthreads();
  int n4 = (t & 127) * 4, mh = (t >> 7) * 4;
  float4 acc[4];
#pragma unroll
  for (int m = 0; m < 4; ++m) acc[m] = (float4){0.f, 0.f, 0.f, 0.f};
  for (int i = 0; i < 32; ++i) {
    float4 wv = *(const float4*)(trW + ((size_t)ks * BDD + d0 + i) * BDD + n4);
#pragma unroll
    for (int m = 0; m < 4; ++m) {
      float g = el[mh + m][i];
      acc[m].x += g * wv.x; acc[m].y += g * wv.y;
      acc[m].z += g * wv.z; acc[m].w += g * wv.w;
    }
  }
#pragma unroll
  for (int m = 0; m < 4; ++m)
    *(float4*)(pt + ((size_t)dq * 512 + (mh + m) * NSP + ks) * BDD + n4) = acc[m];
}

// ---------- dec partials (fused trans-reduce + bias): pd[dq][m][n] ----------
__global__ void k_dec_part(const float* __restrict__ pt, const float* __restrict__ trB,
                           const float* __restrict__ decW, float* __restrict__ pd) {
  __shared__ float tl[8][64];
  int dq = blockIdx.x, mt = blockIdx.y;
  int m0 = mt * 8, d0 = dq * 64;
  int t = threadIdx.x;
  {
    int r = t >> 5, c = t & 31;
    int m = m0 + r;
    float s1 = 0.f, s2 = 0.f;
#pragma unroll
    for (int p = 0; p < 16; ++p) {
      const float* qp = pt + ((size_t)p * 512 + m) * BDD + d0;
      s1 += qp[c]; s2 += qp[c + 32];
    }
    tl[r][c] = s1 + trB[(m & 63) * BDD + d0 + c];
    tl[r][c + 32] = s2 + trB[(m & 63) * BDD + d0 + c + 32];
  }
  __syncthreads();
  int n4 = t * 4;
  float4 acc[8];
#pragma unroll
  for (int m = 0; m < 8; ++m) acc[m] = (float4){0.f, 0.f, 0.f, 0.f};
  for (int i = 0; i < 64; ++i) {
    float4 wv = *(const float4*)(decW + (d0 + i) * DD + n4);
#pragma unroll
    for (int m = 0; m < 8; ++m) {
      float g = tl[m][i];
      acc[m].x += g * wv.x; acc[m].y += g * wv.y;
      acc[m].z += g * wv.z; acc[m].w += g * wv.w;
    }
  }
#pragma unroll
  for (int m = 0; m < 8; ++m)
    *(float4*)(pd + ((size_t)dq * 512 + m0 + m) * DD + n4) = acc[m];
}

// ---------- reduce dec partials + bias -> decT[b][n][ks] bf16 ----------
__global__ void red_dec(const float* __restrict__ pd, const float* __restrict__ decB,
                        u16* __restrict__ decT) {
  __shared__ u16 st[64][34];
  int nt = blockIdx.x, b = blockIdx.y;
  int n0 = nt * 32;
  int t = threadIdx.x;
  int nn = t & 31, kg = t >> 5;
  float db = decB[n0 + nn];
#pragma unroll
  for (int ki = 0; ki < 8; ++ki) {
    int ks = kg * 8 + ki;
    float s = db;
#pragma unroll
    for (int p = 0; p < 8; ++p)
      s += pd[((size_t)p * 512 + b * NSP + ks) * DD + n0 + nn];
    st[ks][nn] = f2bf(s);
  }
  __syncthreads();
  int nr = t >> 3, kseg = (t & 7) * 8;
  uint4 v;
  v.x = st[kseg + 0][nr] | ((u32)st[kseg + 1][nr] << 16);
  v.y = st[kseg + 2][nr] | ((u32)st[kseg + 3][nr] << 16);
  v.z = st[kseg + 4][nr] | ((u32)st[kseg + 5][nr] << 16);
  v.w = st[kseg + 6][nr] | ((u32)st[kseg + 7][nr] << 16);
  *(uint4*)(decT + ((size_t)b * DD + n0 + nr) * NSP + kseg) = v;
}

// ---------- fused gate GEMM + scatter + sigmoid*flow ----------
// BM=128, BN=256, BK=64; 512 threads (8 waves 2x4); dbuf 96KB.
// Fine-grained: 2 phases per K-tile, stage-halves between ds_reads and MFMAs,
// ONE vmcnt(0)+barrier per K-tile. Slots static via manual unroll-by-2.

#define STAGE_A(sl, k0, p)                                                  \
  { int e = (p)*512 + t; int row = e >> 3, csrc = ((e & 7) ^ (row & 7)) * 8; \
    gl_lds16(tokbf + (size_t)(m0 + row) * DD + (k0) + csrc, &As[sl][e * 8]); }
#define STAGE_B(sl, k0, p)                                                  \
  { int e = (p)*512 + t; int row = e >> 3, csrc = ((e & 7) ^ (row & 7)) * 8; \
    gl_lds16(gwt + (size_t)(n0 + row) * DD + (k0) + csrc, &Bs[sl][e * 8]); }

#define PHASE(sl, ks, ACC, STAGE_STMT)                                       \
  {                                                                          \
    bf16x8 af[4], bfv[4];                                                    \
    int g = (ks)*4 + lh;                                                     \
    _Pragma("unroll")                                                        \
    for (int mi = 0; mi < 4; ++mi) {                                         \
      int r = wr * 64 + mi * 16 + l15;                                       \
      af[mi] = *(const bf16x8*)&As[sl][r * 64 + (g ^ (r & 7)) * 8];          \
    }                                                                        \
    _Pragma("unroll")                                                        \
    for (int ni = 0; ni < 4; ++ni) {                                         \
      int r = wc * 64 + ni * 16 + l15;                                       \
      bfv[ni] = *(const bf16x8*)&Bs[sl][r * 64 + (g ^ (r & 7)) * 8];         \
    }                                                                        \
    STAGE_STMT;                                                              \
    __builtin_amdgcn_s_setprio(1);                                           \
    _Pragma("unroll")                                                        \
    for (int mi = 0; mi < 4; ++mi)                                           \
      _Pragma("unroll")                                                      \
      for (int ni = 0; ni < 4; ++ni)                                         \
        ACC[mi][ni] = __builtin_amdgcn_mfma_f32_16x16x32_bf16(af[mi], bfv[ni], ACC[mi][ni], 0, 0, 0); \
    __builtin_amdgcn_s_setprio(0);                                           \
  }

__global__ __launch_bounds__(512, 2) void k_out(const u16* __restrict__ tokbf,
                                                const u16* __restrict__ gwt,
                                                const u16* __restrict__ inflbf,
                                                const u16* __restrict__ decT,
                                                const float* __restrict__ gateB,
                                                float* __restrict__ outp) {
  __shared__ u16 As[2][128 * 64];
  __shared__ u16 Bs[2][256 * 64];
  int t = threadIdx.x;
  int l = t & 63, w = t >> 6;
  int wr = w >> 2, wc = w & 3;  // 2 x 4 waves, 64x64 per wave
  int m0 = blockIdx.x * 128, n0 = blockIdx.y * 256;
  int l15 = l & 15, lh = l >> 4;

  f32x4 accg[4][4];
#pragma unroll
  for (int i = 0; i < 4; ++i)
#pragma unroll
    for (int j = 0; j < 4; ++j) accg[i][j] = (f32x4){0.f, 0.f, 0.f, 0.f};

  // prologue: tile 0 -> slot 0
  STAGE_A(0, 0, 0); STAGE_B(0, 0, 0); STAGE_B(0, 0, 1);
  STAGE_A(0, 0, 1); STAGE_B(0, 0, 2); STAGE_B(0, 0, 3);
  asm volatile("s_waitcnt vmcnt(0)" ::: "memory");
  __builtin_amdgcn_s_barrier();

#pragma unroll 1
  for (int i = 0; i < 8; ++i) {
    int kb = i * 128 + 64;   // tile 2i+1
    int kc = kb + 64;        // tile 2i+2
    // compute tile 2i from slot 0; stage tile 2i+1 -> slot 1
    PHASE(0, 0, accg, { STAGE_A(1, kb, 0); STAGE_B(1, kb, 0); STAGE_B(1, kb, 1); });
    PHASE(0, 1, accg, { STAGE_A(1, kb, 1); STAGE_B(1, kb, 2); STAGE_B(1, kb, 3); });
    asm volatile("s_waitcnt vmcnt(0)" ::: "memory");
    __builtin_amdgcn_s_barrier();
    // compute tile 2i+1 from slot 1; stage tile 2i+2 -> slot 0
    if (i < 7) {
      PHASE(1, 0, accg, { STAGE_A(0, kc, 0); STAGE_B(0, kc, 0); STAGE_B(0, kc, 1); });
      PHASE(1, 1, accg, { STAGE_A(0, kc, 1); STAGE_B(0, kc, 2); STAGE_B(0, kc, 3); });
    } else {
      PHASE(1, 0, accg, {});
      PHASE(1, 1, accg, {});
    }
    asm volatile("s_waitcnt vmcnt(0)" ::: "memory");
    __builtin_amdgcn_s_barrier();
  }

  // scatter pass: K = 64 splats, stage into slot 0
  int b = m0 >> 11;
  int s0m = m0 & 2047;
#pragma unroll
  for (int p = 0; p < 2; ++p) {
    int e = p * 512 + t;
    int row = e >> 3, csrc = ((e & 7) ^ (row & 7)) * 8;
    gl_lds16(inflbf + ((size_t)b * SS + s0m + row) * NSP + csrc, &As[0][e * 8]);
  }
#pragma unroll
  for (int p = 0; p < 4; ++p) {
    int e = p * 512 + t;
    int row = e >> 3, csrc = ((e & 7) ^ (row & 7)) * 8;
    gl_lds16(decT + ((size_t)b * DD + n0 + row) * NSP + csrc, &Bs[0][e * 8]);
  }
  asm volatile("s_waitcnt vmcnt(0)" ::: "memory");
  __builtin_amdgcn_s_barrier();

  f32x4 accf[4][4];
#pragma unroll
  for (int i = 0; i < 4; ++i)
#pragma unroll
    for (int j = 0; j < 4; ++j) accf[i][j] = (f32x4){0.f, 0.f, 0.f, 0.f};
  PHASE(0, 0, accf, {});
  PHASE(0, 1, accf, {});

  float gb[4];
#pragma unroll
  for (int ni = 0; ni < 4; ++ni) gb[ni] = gateB[n0 + wc * 64 + ni * 16 + l15];
#pragma unroll
  for (int mi = 0; mi < 4; ++mi)
#pragma unroll
    for (int ni = 0; ni < 4; ++ni)
#pragma unroll
      for (int r = 0; r < 4; ++r) {
        int mr = m0 + wr * 64 + mi * 16 + lh * 4 + r;
        int nc = n0 + wc * 64 + ni * 16 + l15;
        float z = accg[mi][ni][r] + gb[ni];
        float gate = 1.f / (1.f + __expf(-z));
        outp[(size_t)mr * DD + nc] = accf[mi][ni][r] * gate;
      }
}

extern "C" void kernel_launch(void* const* d_in, const int* in_sizes, int n_in,
                              void* d_out, int out_size, void* d_ws, size_t ws_size,
                              hipStream_t stream) {
  const float* tok = (const float*)d_in[0];
  const float* infl = (const float*)d_in[1];
  const float* encW = (const float*)d_in[2];
  const float* encB = (const float*)d_in[3];
  const float* trW = (const float*)d_in[4];
  const float* trB = (const float*)d_in[5];
  const float* decW = (const float*)d_in[6];
  const float* decB = (const float*)d_in[7];
  const float* gw = (const float*)d_in[8];
  const float* gateB = (const float*)d_in[9];
  float* outp = (float*)d_out;

  char* wsp = (char*)d_ws;
  u16* tokbf = (u16*)(wsp);                    // 33,554,432 B
  u16* gwt = (u16*)(wsp + 33554432);           //  2,097,152 B
  u16* inflbf = (u16*)(wsp + 35651584);        //  2,097,152 B
  float* rtot = (float*)(wsp + 37748736);      //      2,048 B
  u16* decT = (u16*)(wsp + 41945088);          //  1,048,576 B
  u16* tokT = (u16*)(wsp + 42993664);          // 33,554,432 B (dead after gather)
  float* pe = (float*)(wsp + 42993664);        //   overlays tokT[0:16MB]
  float* pt = (float*)(wsp + 42993664 + 16777216);  // overlays tokT[16:32MB]
  u16* inflT = (u16*)(wsp + 76548096);         //  2,097,152 B
  float* rsum = (float*)(wsp + 78645248);      //     65,536 B
  float* scratch = (float*)(wsp + 78710784);   // 16,777,216 B: pg then pd (end ~95.5 MB)

  k_prep_tok<<<dim3(16, 256), dim3(256), 0, stream>>>(tok, tokbf, tokT);
  k_prep_infl<<<dim3(256), dim3(256), 0, stream>>>(infl, inflbf, inflT, rsum);
  k_tot_fin<<<dim3(1), dim3(512), 0, stream>>>(rsum, rtot);
  k_gatewt<<<dim3(32, 32), dim3(256), 0, stream>>>(gw, gwt);
  k_gather_mfma<<<dim3(16, 8, 4), dim3(256), 0, stream>>>(inflT, tokT, scratch);
  k_enc_part<<<dim3(16, 64), dim3(256), 0, stream>>>(scratch, rtot, encW, pe);
  k_trans_part<<<dim3(16, 64), dim3(256), 0, stream>>>(pe, encB, trW, pt);
  k_dec_part<<<dim3(8, 64), dim3(256), 0, stream>>>(pt, trB, decW, scratch);
  red_dec<<<dim3(32, 8), dim3(256), 0, stream>>>(scratch, decB, decT);
  k_out<<<dim3(128, 4), dim3(512), 0, stream>>>(tokbf, gwt, inflbf, decT, gateB, outp);
}